// Round 21
// baseline (163.693 us; speedup 1.0000x reference)
//
#include <hip/hip_runtime.h>

// MHA fused forward: B=4, T=2048, C=1024, H=16, DH=64
#define T_SEQ 2048
#define C_DIM 1024
#define H_NUM 16
#define DHD   64
#define B_NUM 4
#define M_ROWS (B_NUM*T_SEQ)   // 8192

typedef __bf16 bf16x8 __attribute__((ext_vector_type(8)));
typedef float  f32x4  __attribute__((ext_vector_type(4)));
typedef unsigned short ushort8 __attribute__((ext_vector_type(8)));
typedef unsigned short ushort4e __attribute__((ext_vector_type(4)));

__device__ __forceinline__ unsigned short f2b(float f){
  return __builtin_bit_cast(unsigned short, (__bf16)f);
}
__device__ __forceinline__ bf16x8 as_bf(ushort8 u){ return __builtin_bit_cast(bf16x8, u); }
__device__ __forceinline__ float exp2fast(float x){ return __builtin_amdgcn_exp2f(x); }

__device__ __forceinline__ void gload16(const void* g, void* l){
  __builtin_amdgcn_global_load_lds(
      (const __attribute__((address_space(1))) void*)g,
      (__attribute__((address_space(3))) void*)l, 16, 0, 0);
}

#define MF(a,b,c) __builtin_amdgcn_mfma_f32_16x16x32_bf16(a,b,c,0,0,0)

// ---------------- prep: x f32->bf16 + coalesced weight pack (LDS transpose) ----------------
__global__ __launch_bounds__(256) void k_prep(const float* __restrict__ x,
                                              const float* __restrict__ wq,
                                              const float* __restrict__ wk,
                                              const float* __restrict__ wv,
                                              const float* __restrict__ wo,
                                              unsigned short* __restrict__ xb,
                                              unsigned short* __restrict__ wt,
                                              unsigned short* __restrict__ wot){
  const int bid = blockIdx.x;
  const int tid = threadIdx.x;
  if (bid < 8192){
    int i = bid*256 + tid;
    float4 f = ((const float4*)x)[i];
    ushort4e o;
    o[0]=f2b(f.x); o[1]=f2b(f.y); o[2]=f2b(f.z); o[3]=f2b(f.w);
    ((ushort4e*)xb)[i] = o;
    return;
  }
  __shared__ __align__(16) unsigned short vr[64][72];
  const int tb = bid - 8192;
  const float* S; int LS; unsigned short* D; int R0, C0; float scale = 1.f;
  if (tb < 768){
    int m = tb >> 8, rem = tb & 255;
    int h = rem >> 4, c0 = rem & 15;
    S = ((m==0)?wq:(m==1)?wk:wv) + (size_t)(h*16 + c0)*64*64;
    LS = 64;
    D = wt; R0 = m*1024 + h*64; C0 = c0*64;
    if (m == 0) scale = 0.125f * 1.4426950408889634f;  // DH^-0.5 * log2(e)
  } else {
    int tb2 = tb - 768;
    int nb = tb2 >> 4, cb = tb2 & 15;
    S = wo + (size_t)(cb*64)*1024 + nb*64;
    LS = 1024;
    D = wot; R0 = nb*64; C0 = cb*64;
  }
  #pragma unroll
  for (int i = 0; i < 2; i++){
    int id2 = tid + i*256;
    int r = id2 >> 3, e8 = (id2 & 7)*8;
    float4 a = *(const float4*)&S[(size_t)r*LS + e8];
    float4 b2 = *(const float4*)&S[(size_t)r*LS + e8 + 4];
    ushort8 u;
    u[0]=f2b(a.x*scale); u[1]=f2b(a.y*scale); u[2]=f2b(a.z*scale); u[3]=f2b(a.w*scale);
    u[4]=f2b(b2.x*scale); u[5]=f2b(b2.y*scale); u[6]=f2b(b2.z*scale); u[7]=f2b(b2.w*scale);
    *(ushort8*)&vr[r][e8 ^ ((r >> 3) << 3)] = u;
  }
  __syncthreads();
  #pragma unroll
  for (int i = 0; i < 2; i++){
    int id2 = tid + i*256;
    int d = id2 >> 3, oc = id2 & 7;
    ushort8 u;
    #pragma unroll
    for (int j = 0; j < 8; j++)
      u[j] = vr[oc*8 + j][d ^ (oc << 3)];
    *(ushort8*)&D[(size_t)(R0 + d)*1024 + C0 + oc*8] = u;
  }
}

// ---------------- GEMM: QKV projection (m97 2-phase 128²) ----------------
// Q/K blocks compute C^T (swapped MFMA operands) so each lane holds 4 consecutive d
// -> vectorized ushort4 stores. V blocks keep original orientation + sigma-permuted
// V^T LDS-transpose epilogue.
__global__ __launch_bounds__(256) void k_gemm_qkv(const unsigned short* __restrict__ xb,
                                                  const unsigned short* __restrict__ wt,
                                                  unsigned short* __restrict__ qo,
                                                  unsigned short* __restrict__ ko,
                                                  unsigned short* __restrict__ vtr){
  __shared__ __align__(16) unsigned short smem[2][128*64];
  const int tid = threadIdx.x, lane = tid & 63, wid = tid >> 6;
  const int g = lane >> 4, tl = lane & 15;
  const int wr = wid >> 1, wc = wid & 1;
  // 2D XCD partition: 4 m-groups x 2 n-groups
  const int id = blockIdx.x;
  const int xcd = id & 7, i = id >> 3;        // 192 blocks per XCD
  const int xm = xcd >> 1, xn = xcd & 1;
  const int mbase = (xm*16 + i/12) * 128, nbase = (xn*12 + i%12) * 128;
  const int sel = nbase >> 10;   // block-uniform
  f32x4 acc[4][4] = {};
  if (sel < 2){
    // ---- main loop, C^T orientation ----
    for (int kk = 0; kk < C_DIM; kk += 64){
      __syncthreads();
      #pragma unroll
      for (int i2 = 0; i2 < 4; i2++){
        const int brow = (wid*4 + i2)*8;
        const int row  = brow + (lane >> 3);
        const int jj   = (lane & 7) ^ (row & 7);
        gload16(&xb[(size_t)(mbase+row)*C_DIM + kk + jj*8], &smem[0][brow*64]);
        gload16(&wt[(size_t)(nbase+row)*C_DIM + kk + jj*8], &smem[1][brow*64]);
      }
      __syncthreads();
      bf16x8 aF[4][2], bF[4][2];
      #pragma unroll
      for (int mb = 0; mb < 4; mb++){
        const int row = wr*64 + mb*16 + tl; const int s7 = row & 7;
        aF[mb][0] = as_bf(*(const ushort8*)&smem[0][row*64 + ((g     ^ s7)*8)]);
        aF[mb][1] = as_bf(*(const ushort8*)&smem[0][row*64 + (((4+g) ^ s7)*8)]);
      }
      #pragma unroll
      for (int nb = 0; nb < 4; nb++){
        const int row = wc*64 + nb*16 + tl; const int s7 = row & 7;
        bF[nb][0] = as_bf(*(const ushort8*)&smem[1][row*64 + ((g     ^ s7)*8)]);
        bF[nb][1] = as_bf(*(const ushort8*)&smem[1][row*64 + (((4+g) ^ s7)*8)]);
      }
      #pragma unroll
      for (int mb = 0; mb < 4; mb++)
        #pragma unroll
        for (int nb = 0; nb < 4; nb++){
          acc[mb][nb] = MF(bF[nb][0], aF[mb][0], acc[mb][nb]);   // swapped: C^T
          acc[mb][nb] = MF(bF[nb][1], aF[mb][1], acc[mb][nb]);
        }
    }
    // epilogue: lane holds C[t = ...+tl][n = ...+g*4+r] -> ushort4 per (mb,nb)
    unsigned short* dst0 = (sel == 0) ? qo : ko;
    const int nloc = (nbase & 1023) + wc*64;
    #pragma unroll
    for (int mb = 0; mb < 4; mb++){
      const int t = mbase + wr*64 + mb*16 + tl;
      const int b = t >> 11, tt = t & 2047;
      #pragma unroll
      for (int nb = 0; nb < 4; nb++){
        const int nw = nloc + nb*16 + g*4;
        const int h = nw >> 6, d0 = nw & 63;
        ushort4e pk;
        #pragma unroll
        for (int r = 0; r < 4; r++) pk[r] = f2b(acc[mb][nb][r]);
        *(ushort4e*)&dst0[(((size_t)(b*H_NUM + h))*T_SEQ + tt)*DHD + d0] = pk;
      }
    }
  } else {
    // ---- main loop, original orientation (V blocks) ----
    for (int kk = 0; kk < C_DIM; kk += 64){
      __syncthreads();
      #pragma unroll
      for (int i2 = 0; i2 < 4; i2++){
        const int brow = (wid*4 + i2)*8;
        const int row  = brow + (lane >> 3);
        const int jj   = (lane & 7) ^ (row & 7);
        gload16(&xb[(size_t)(mbase+row)*C_DIM + kk + jj*8], &smem[0][brow*64]);
        gload16(&wt[(size_t)(nbase+row)*C_DIM + kk + jj*8], &smem[1][brow*64]);
      }
      __syncthreads();
      bf16x8 aF[4][2], bF[4][2];
      #pragma unroll
      for (int mb = 0; mb < 4; mb++){
        const int row = wr*64 + mb*16 + tl; const int s7 = row & 7;
        aF[mb][0] = as_bf(*(const ushort8*)&smem[0][row*64 + ((g     ^ s7)*8)]);
        aF[mb][1] = as_bf(*(const ushort8*)&smem[0][row*64 + (((4+g) ^ s7)*8)]);
      }
      #pragma unroll
      for (int nb = 0; nb < 4; nb++){
        const int row = wc*64 + nb*16 + tl; const int s7 = row & 7;
        bF[nb][0] = as_bf(*(const ushort8*)&smem[1][row*64 + ((g     ^ s7)*8)]);
        bF[nb][1] = as_bf(*(const ushort8*)&smem[1][row*64 + (((4+g) ^ s7)*8)]);
      }
      #pragma unroll
      for (int mb = 0; mb < 4; mb++)
        #pragma unroll
        for (int nb = 0; nb < 4; nb++){
          acc[mb][nb] = MF(aF[mb][0], bF[nb][0], acc[mb][nb]);
          acc[mb][nb] = MF(aF[mb][1], bF[nb][1], acc[mb][nb]);
        }
    }
    // V epilogue: transpose 128x128 tile through swizzled LDS, write sigma-permuted V^T.
    __syncthreads();                       // all waves done reading smem
    unsigned short* tr = &smem[0][0];      // 128*128 ushorts = 32 KB
    #pragma unroll
    for (int mb = 0; mb < 4; mb++){
      #pragma unroll
      for (int nb = 0; nb < 4; nb++){
        const int n = wc*64 + nb*16 + tl;
        const int m0 = wr*64 + mb*16 + g*4;
        ushort4e pk;
        #pragma unroll
        for (int r = 0; r < 4; r++) pk[r] = f2b(acc[mb][nb][r]);
        *(ushort4e*)&tr[n*128 + (m0 ^ ((n & 15) << 3))] = pk;
      }
    }
    __syncthreads();
    const int hbase = (nbase - 2048) >> 6;
    const int b = mbase >> 11, tloc = mbase & 2047;
    const int n = tid >> 1, half = tid & 1;
    unsigned short* vdst = vtr + (((size_t)(b*H_NUM + hbase + (n >> 6)))*DHD + (n & 63))*T_SEQ
                           + tloc + half*64;
    const int nx = (n & 15) << 3;
    #pragma unroll
    for (int c8 = 0; c8 < 8; c8++){
      const int t0 = half*64 + (c8 >> 2)*32 + (c8 & 3)*4;
      ushort4e lo = *(const ushort4e*)&tr[n*128 + ((t0     ) ^ nx)];
      ushort4e hi = *(const ushort4e*)&tr[n*128 + ((t0 + 16) ^ nx)];
      ushort8 u;
      #pragma unroll
      for (int e = 0; e < 4; e++){ u[e] = lo[e]; u[4+e] = hi[e]; }
      *(ushort8*)&vdst[c8*8] = u;
    }
  }
}

// ---------------- Flash attention (causal): 8 waves x 32 rows, one 256-row Q-tile/block ----------------
// grid 512 = 2 blocks/CU. Dispatch: k=id>>3 -> bh=8*(id&7)+(k&7), qsel=k>>3 pairs (q,q+4)
// -> qt = qsel<4 ? qsel : 11-qsel (co-resident pair sums 18 iters, shares bh).
// KVBLK=128; P in-register (sigma); V^T global sigma-permuted -> V frag = b128.
__global__ __launch_bounds__(512) void k_flash(const unsigned short* __restrict__ q,
                                               const unsigned short* __restrict__ k,
                                               const unsigned short* __restrict__ vtg,
                                               unsigned short* __restrict__ o){
  __shared__ __align__(16) unsigned short kbufs[2][128*64];   // [s][d]
  __shared__ __align__(16) unsigned short vbufs[2][64*128];   // [d][t-local]
  const int tid = threadIdx.x, lane = tid & 63, w = tid >> 6;
  const int g = lane >> 4, tl = lane & 15;
  const int id = blockIdx.x;
  const int kslot = id >> 3;
  const int bh = (id & 7)*8 + (kslot & 7);
  const int qsel = kslot >> 3;
  const int qt = (qsel < 4) ? qsel : (11 - qsel);
  const int b = bh >> 4, h = bh & 15;
  const unsigned short* qb = q   + (size_t)bh * T_SEQ * DHD;
  const unsigned short* kb = k   + (size_t)bh * T_SEQ * DHD;
  const unsigned short* vb = vtg + (size_t)bh * (size_t)DHD * T_SEQ;
  const int lrow = lane >> 3, lj = lane & 7;
  const int s7 = tl & 7;
  // V staging lane geometry
  const int vre = lane >> 4;            // row extra (0..3)
  const int vh  = (lane >> 3) & 1;      // col half
  const int vcc = lane & 7;             // chunk within half

  const int tbase = qt * 256;
  const int trow0 = tbase + w * 32;
  const int tmax = trow0 + 31;
  bf16x8 qF[2][2];
  #pragma unroll
  for (int tf = 0; tf < 2; tf++)
    #pragma unroll
    for (int ks = 0; ks < 2; ks++)
      qF[tf][ks] = as_bf(*(const ushort8*)&qb[(size_t)(trow0 + tf*16 + tl)*DHD + ks*32 + g*8]);
  f32x4 acc[2][4] = {};
  float mreg[2] = {-1e30f, -1e30f}, lreg[2] = {0.f, 0.f};
  const int nkt = 2*qt + 2;           // 128-wide kv tiles
  // prologue: stage tile 0 into buf 0
  #pragma unroll
  for (int i = 0; i < 2; i++){
    const int krow = i*64 + w*8 + lrow;
    const int kjj  = lj ^ (krow & 7);
    gload16(&kb[(size_t)krow*DHD + kjj*8], &kbufs[0][(i*64 + w*8)*64]);
    const int vrow = i*32 + w*4 + vre;
    const int vjj  = vcc ^ (vrow & 7);
    gload16(&vb[(size_t)vrow*T_SEQ + vh*64 + vjj*8], &vbufs[0][(i*32 + w*4)*128]);
  }
  __syncthreads();
  for (int kti = 0; kti < nkt; ++kti){
    const int cur = kti & 1;
    const int kbase = kti * 128;
    if (kti + 1 < nkt){
      const int kb2 = kbase + 128;
      #pragma unroll
      for (int i = 0; i < 2; i++){
        const int krow = i*64 + w*8 + lrow;
        const int kjj  = lj ^ (krow & 7);
        gload16(&kb[(size_t)(kb2+krow)*DHD + kjj*8], &kbufs[cur^1][(i*64 + w*8)*64]);
        const int vrow = i*32 + w*4 + vre;
        const int vjj  = vcc ^ (vrow & 7);
        gload16(&vb[(size_t)vrow*T_SEQ + kb2 + vh*64 + vjj*8], &vbufs[cur^1][(i*32 + w*4)*128]);
      }
    }
    if (kbase <= tmax){
      const unsigned short* kcur = kbufs[cur];
      const unsigned short* vcur = vbufs[cur];
      f32x4 st[2][8] = {};
      __builtin_amdgcn_s_setprio(1);
      #pragma unroll
      for (int sf = 0; sf < 8; sf++){
        const int row = sf*16 + tl;
        const int r7 = row & 7;
        bf16x8 kf0 = as_bf(*(const ushort8*)&kcur[row*64 + ((g     ^ r7)*8)]);
        bf16x8 kf1 = as_bf(*(const ushort8*)&kcur[row*64 + (((4+g) ^ r7)*8)]);
        #pragma unroll
        for (int tf = 0; tf < 2; tf++){
          st[tf][sf] = MF(kf0, qF[tf][0], st[tf][sf]);
          st[tf][sf] = MF(kf1, qF[tf][1], st[tf][sf]);
        }
      }
      __builtin_amdgcn_s_setprio(0);
      if (kbase + 127 > trow0){   // causal mask on near-diagonal tiles
        #pragma unroll
        for (int tf = 0; tf < 2; tf++){
          int tg = trow0 + tf*16 + tl;
          #pragma unroll
          for (int sf = 0; sf < 8; sf++)
            #pragma unroll
            for (int r = 0; r < 4; r++)
              if (kbase + sf*16 + g*4 + r > tg) st[tf][sf][r] = -1e30f;
        }
      }
      bf16x8 pa[2][4];
      #pragma unroll
      for (int tf = 0; tf < 2; tf++){
        float mloc = -1e30f;
        #pragma unroll
        for (int sf = 0; sf < 8; sf++)
          #pragma unroll
          for (int r = 0; r < 4; r++) mloc = fmaxf(mloc, st[tf][sf][r]);
        if (__any(mloc > mreg[tf] + 8.f)){   // lazy-max (T13)
          float mrow = fmaxf(mloc, __shfl_xor(mloc, 16));
          mrow = fmaxf(mrow, __shfl_xor(mrow, 32));
          float mnew = fmaxf(mreg[tf], mrow);
          float alpha = exp2fast(mreg[tf] - mnew);
          mreg[tf] = mnew;
          lreg[tf] *= alpha;
          #pragma unroll
          for (int df = 0; df < 4; df++)
            #pragma unroll
            for (int r = 0; r < 4; r++) acc[tf][df][r] *= alpha;
        }
        float sum = 0.f;
        #pragma unroll
        for (int q4 = 0; q4 < 4; q4++){
          ushort8 uu;
          #pragma unroll
          for (int r = 0; r < 4; r++){
            float p0 = exp2fast(st[tf][2*q4  ][r] - mreg[tf]);
            float p1 = exp2fast(st[tf][2*q4+1][r] - mreg[tf]);
            sum += p0 + p1;
            uu[r]   = f2b(p0);
            uu[4+r] = f2b(p1);
          }
          pa[tf][q4] = as_bf(uu);
        }
        lreg[tf] += sum;   // per-lane partial; reduced at epilogue
      }
      __builtin_amdgcn_s_setprio(1);
      #pragma unroll
      for (int df = 0; df < 4; df++){
        const int row = df*16 + tl;
        bf16x8 vfr[4];
        #pragma unroll
        for (int q4 = 0; q4 < 4; q4++)
          vfr[q4] = as_bf(*(const ushort8*)&vcur[row*128 + (q4 >> 1)*64 + (((4*(q4 & 1) + g) ^ s7)*8)]);
        #pragma unroll
        for (int tf = 0; tf < 2; tf++)
          #pragma unroll
          for (int q4 = 0; q4 < 4; q4++)
            acc[tf][df] = MF(vfr[q4], pa[tf][q4], acc[tf][df]);
      }
      __builtin_amdgcn_s_setprio(0);
    }
    __syncthreads();
  }
  #pragma unroll
  for (int tf = 0; tf < 2; tf++){
    float l = lreg[tf];
    l += __shfl_xor(l, 16);
    l += __shfl_xor(l, 32);
    float inv = 1.f / l;
    int tg = trow0 + tf*16 + tl;
    #pragma unroll
    for (int df = 0; df < 4; df++){
      ushort4e ov;
      #pragma unroll
      for (int r = 0; r < 4; r++) ov[r] = f2b(acc[tf][df][r] * inv);
      *(ushort4e*)&o[((size_t)(b*T_SEQ + tg))*C_DIM + h*DHD + df*16 + g*4] = ov;
    }
  }
}

// ---------------- GEMM: output projection + bias (128-tile m97 structure) ----------------
__global__ __launch_bounds__(256) void k_gemm_proj(const unsigned short* __restrict__ ab,
                                                   const unsigned short* __restrict__ wot,
                                                   const float* __restrict__ bo,
                                                   float* __restrict__ out){
  __shared__ __align__(16) unsigned short a_lds[128*64];
  __shared__ __align__(16) unsigned short b_lds[128*64];
  const int tid = threadIdx.x, lane = tid & 63, wid = tid >> 6;
  const int g = lane >> 4, tl = lane & 15;
  const int wr = wid >> 1, wc = wid & 1;
  const int id = blockIdx.x;
  const int swz = (id & 7)*64 + (id >> 3);
  const int mbase = (swz >> 3) * 128, nbase = (swz & 7) * 128;
  f32x4 acc[4][4] = {};
  for (int kk = 0; kk < C_DIM; kk += 64){
    __syncthreads();
    #pragma unroll
    for (int i = 0; i < 4; i++){
      const int brow = (wid*4 + i)*8;
      const int row  = brow + (lane >> 3);
      const int jj   = (lane & 7) ^ (row & 7);
      gload16(&ab[(size_t)(mbase+row)*C_DIM + kk + jj*8],  &a_lds[brow*64]);
      gload16(&wot[(size_t)(nbase+row)*C_DIM + kk + jj*8], &b_lds[brow*64]);
    }
    __syncthreads();
    bf16x8 aF[4][2], bF[4][2];
    #pragma unroll
    for (int mb = 0; mb < 4; mb++){
      const int row = wr*64 + mb*16 + tl; const int s7 = row & 7;
      aF[mb][0] = as_bf(*(const ushort8*)&a_lds[row*64 + ((g     ^ s7)*8)]);
      aF[mb][1] = as_bf(*(const ushort8*)&a_lds[row*64 + (((4+g) ^ s7)*8)]);
    }
    #pragma unroll
    for (int nb = 0; nb < 4; nb++){
      const int row = wc*64 + nb*16 + tl; const int s7 = row & 7;
      bF[nb][0] = as_bf(*(const ushort8*)&b_lds[row*64 + ((g     ^ s7)*8)]);
      bF[nb][1] = as_bf(*(const ushort8*)&b_lds[row*64 + (((4+g) ^ s7)*8)]);
    }
    #pragma unroll
    for (int mb = 0; mb < 4; mb++)
      #pragma unroll
      for (int nb = 0; nb < 4; nb++){
        acc[mb][nb] = MF(aF[mb][0], bF[nb][0], acc[mb][nb]);
        acc[mb][nb] = MF(aF[mb][1], bF[nb][1], acc[mb][nb]);
      }
  }
  #pragma unroll
  for (int mb = 0; mb < 4; mb++){
    #pragma unroll
    for (int nb = 0; nb < 4; nb++){
      #pragma unroll
      for (int r = 0; r < 4; r++){
        int gr = mbase + wr*64 + mb*16 + g*4 + r;
        int gc = nbase + wc*64 + nb*16 + tl;
        out[(size_t)gr*C_DIM + gc] = acc[mb][nb][r] + bo[gc];
      }
    }
  }
}

extern "C" void kernel_launch(void* const* d_in, const int* in_sizes, int n_in,
                              void* d_out, int out_size, void* d_ws, size_t ws_size,
                              hipStream_t stream){
  const float* x  = (const float*)d_in[0];
  const float* Wq = (const float*)d_in[1];
  const float* Wk = (const float*)d_in[2];
  const float* Wv = (const float*)d_in[3];
  const float* Wo = (const float*)d_in[4];
  const float* bo = (const float*)d_in[5];
  float* out = (float*)d_out;

  char* p = (char*)d_ws;
  unsigned short* xb  = (unsigned short*)p; p += (size_t)M_ROWS*C_DIM*2;   // 16MB
  unsigned short* wt  = (unsigned short*)p; p += (size_t)3*C_DIM*C_DIM*2;  // 6MB
  unsigned short* wot = (unsigned short*)p; p += (size_t)C_DIM*C_DIM*2;    // 2MB
  unsigned short* Qb  = (unsigned short*)p; p += (size_t)M_ROWS*C_DIM*2;   // 16MB
  unsigned short* Kb  = (unsigned short*)p; p += (size_t)M_ROWS*C_DIM*2;   // 16MB
  unsigned short* Vtr = (unsigned short*)p; p += (size_t)M_ROWS*C_DIM*2;   // 16MB (sigma-permuted V^T)
  unsigned short* attn = xb;   // reuse: xb dead after k_gemm_qkv

  hipLaunchKernelGGL(k_prep, dim3(8192 + 1024), dim3(256), 0, stream,
                     x, Wq, Wk, Wv, Wo, xb, wt, wot);
  hipLaunchKernelGGL(k_gemm_qkv, dim3(1536), dim3(256), 0, stream,
                     xb, wt, Qb, Kb, Vtr);
  hipLaunchKernelGGL(k_flash, dim3(512), dim3(512), 0, stream,
                     Qb, Kb, Vtr, attn);
  hipLaunchKernelGGL(k_gemm_proj, dim3(512), dim3(256), 0, stream,
                     attn, wot, bo, out);
}

// Round 22
// 162.967 us; speedup vs baseline: 1.0045x; 1.0045x over previous
//
#include <hip/hip_runtime.h>

// MHA fused forward: B=4, T=2048, C=1024, H=16, DH=64
#define T_SEQ 2048
#define C_DIM 1024
#define H_NUM 16
#define DHD   64
#define B_NUM 4
#define M_ROWS (B_NUM*T_SEQ)   // 8192

typedef __bf16 bf16x8 __attribute__((ext_vector_type(8)));
typedef float  f32x4  __attribute__((ext_vector_type(4)));
typedef unsigned short ushort8 __attribute__((ext_vector_type(8)));
typedef unsigned short ushort4e __attribute__((ext_vector_type(4)));

__device__ __forceinline__ unsigned short f2b(float f){
  return __builtin_bit_cast(unsigned short, (__bf16)f);
}
__device__ __forceinline__ bf16x8 as_bf(ushort8 u){ return __builtin_bit_cast(bf16x8, u); }
__device__ __forceinline__ float exp2fast(float x){ return __builtin_amdgcn_exp2f(x); }

__device__ __forceinline__ void gload16(const void* g, void* l){
  __builtin_amdgcn_global_load_lds(
      (const __attribute__((address_space(1))) void*)g,
      (__attribute__((address_space(3))) void*)l, 16, 0, 0);
}

#define MF(a,b,c) __builtin_amdgcn_mfma_f32_16x16x32_bf16(a,b,c,0,0,0)

// ---------------- prep: x f32->bf16 + coalesced weight pack (LDS transpose) ----------------
__global__ __launch_bounds__(256) void k_prep(const float* __restrict__ x,
                                              const float* __restrict__ wq,
                                              const float* __restrict__ wk,
                                              const float* __restrict__ wv,
                                              const float* __restrict__ wo,
                                              unsigned short* __restrict__ xb,
                                              unsigned short* __restrict__ wt,
                                              unsigned short* __restrict__ wot){
  const int bid = blockIdx.x;
  const int tid = threadIdx.x;
  if (bid < 8192){
    int i = bid*256 + tid;
    float4 f = ((const float4*)x)[i];
    ushort4e o;
    o[0]=f2b(f.x); o[1]=f2b(f.y); o[2]=f2b(f.z); o[3]=f2b(f.w);
    ((ushort4e*)xb)[i] = o;
    return;
  }
  __shared__ __align__(16) unsigned short vr[64][72];
  const int tb = bid - 8192;
  const float* S; int LS; unsigned short* D; int R0, C0; float scale = 1.f;
  if (tb < 768){
    int m = tb >> 8, rem = tb & 255;
    int h = rem >> 4, c0 = rem & 15;
    S = ((m==0)?wq:(m==1)?wk:wv) + (size_t)(h*16 + c0)*64*64;
    LS = 64;
    D = wt; R0 = m*1024 + h*64; C0 = c0*64;
    if (m == 0) scale = 0.125f * 1.4426950408889634f;  // DH^-0.5 * log2(e)
  } else {
    int tb2 = tb - 768;
    int nb = tb2 >> 4, cb = tb2 & 15;
    S = wo + (size_t)(cb*64)*1024 + nb*64;
    LS = 1024;
    D = wot; R0 = nb*64; C0 = cb*64;
  }
  #pragma unroll
  for (int i = 0; i < 2; i++){
    int id2 = tid + i*256;
    int r = id2 >> 3, e8 = (id2 & 7)*8;
    float4 a = *(const float4*)&S[(size_t)r*LS + e8];
    float4 b2 = *(const float4*)&S[(size_t)r*LS + e8 + 4];
    ushort8 u;
    u[0]=f2b(a.x*scale); u[1]=f2b(a.y*scale); u[2]=f2b(a.z*scale); u[3]=f2b(a.w*scale);
    u[4]=f2b(b2.x*scale); u[5]=f2b(b2.y*scale); u[6]=f2b(b2.z*scale); u[7]=f2b(b2.w*scale);
    *(ushort8*)&vr[r][e8 ^ ((r >> 3) << 3)] = u;
  }
  __syncthreads();
  #pragma unroll
  for (int i = 0; i < 2; i++){
    int id2 = tid + i*256;
    int d = id2 >> 3, oc = id2 & 7;
    ushort8 u;
    #pragma unroll
    for (int j = 0; j < 8; j++)
      u[j] = vr[oc*8 + j][d ^ (oc << 3)];
    *(ushort8*)&D[(size_t)(R0 + d)*1024 + C0 + oc*8] = u;
  }
}

// ---------------- GEMM: QKV projection (m97 2-phase 128²) ----------------
// Q/K blocks compute C^T (swapped MFMA operands) -> vectorized ushort4 stores.
// V blocks keep original orientation + sigma-permuted V^T LDS-transpose epilogue.
__global__ __launch_bounds__(256) void k_gemm_qkv(const unsigned short* __restrict__ xb,
                                                  const unsigned short* __restrict__ wt,
                                                  unsigned short* __restrict__ qo,
                                                  unsigned short* __restrict__ ko,
                                                  unsigned short* __restrict__ vtr){
  __shared__ __align__(16) unsigned short smem[2][128*64];
  const int tid = threadIdx.x, lane = tid & 63, wid = tid >> 6;
  const int g = lane >> 4, tl = lane & 15;
  const int wr = wid >> 1, wc = wid & 1;
  const int id = blockIdx.x;
  const int xcd = id & 7, i = id >> 3;        // 192 blocks per XCD
  const int xm = xcd >> 1, xn = xcd & 1;
  const int mbase = (xm*16 + i/12) * 128, nbase = (xn*12 + i%12) * 128;
  const int sel = nbase >> 10;   // block-uniform
  f32x4 acc[4][4] = {};
  if (sel < 2){
    for (int kk = 0; kk < C_DIM; kk += 64){
      __syncthreads();
      #pragma unroll
      for (int i2 = 0; i2 < 4; i2++){
        const int brow = (wid*4 + i2)*8;
        const int row  = brow + (lane >> 3);
        const int jj   = (lane & 7) ^ (row & 7);
        gload16(&xb[(size_t)(mbase+row)*C_DIM + kk + jj*8], &smem[0][brow*64]);
        gload16(&wt[(size_t)(nbase+row)*C_DIM + kk + jj*8], &smem[1][brow*64]);
      }
      __syncthreads();
      bf16x8 aF[4][2], bF[4][2];
      #pragma unroll
      for (int mb = 0; mb < 4; mb++){
        const int row = wr*64 + mb*16 + tl; const int s7 = row & 7;
        aF[mb][0] = as_bf(*(const ushort8*)&smem[0][row*64 + ((g     ^ s7)*8)]);
        aF[mb][1] = as_bf(*(const ushort8*)&smem[0][row*64 + (((4+g) ^ s7)*8)]);
      }
      #pragma unroll
      for (int nb = 0; nb < 4; nb++){
        const int row = wc*64 + nb*16 + tl; const int s7 = row & 7;
        bF[nb][0] = as_bf(*(const ushort8*)&smem[1][row*64 + ((g     ^ s7)*8)]);
        bF[nb][1] = as_bf(*(const ushort8*)&smem[1][row*64 + (((4+g) ^ s7)*8)]);
      }
      #pragma unroll
      for (int mb = 0; mb < 4; mb++)
        #pragma unroll
        for (int nb = 0; nb < 4; nb++){
          acc[mb][nb] = MF(bF[nb][0], aF[mb][0], acc[mb][nb]);   // swapped: C^T
          acc[mb][nb] = MF(bF[nb][1], aF[mb][1], acc[mb][nb]);
        }
    }
    unsigned short* dst0 = (sel == 0) ? qo : ko;
    const int nloc = (nbase & 1023) + wc*64;
    #pragma unroll
    for (int mb = 0; mb < 4; mb++){
      const int t = mbase + wr*64 + mb*16 + tl;
      const int b = t >> 11, tt = t & 2047;
      #pragma unroll
      for (int nb = 0; nb < 4; nb++){
        const int nw = nloc + nb*16 + g*4;
        const int h = nw >> 6, d0 = nw & 63;
        ushort4e pk;
        #pragma unroll
        for (int r = 0; r < 4; r++) pk[r] = f2b(acc[mb][nb][r]);
        *(ushort4e*)&dst0[(((size_t)(b*H_NUM + h))*T_SEQ + tt)*DHD + d0] = pk;
      }
    }
  } else {
    for (int kk = 0; kk < C_DIM; kk += 64){
      __syncthreads();
      #pragma unroll
      for (int i2 = 0; i2 < 4; i2++){
        const int brow = (wid*4 + i2)*8;
        const int row  = brow + (lane >> 3);
        const int jj   = (lane & 7) ^ (row & 7);
        gload16(&xb[(size_t)(mbase+row)*C_DIM + kk + jj*8], &smem[0][brow*64]);
        gload16(&wt[(size_t)(nbase+row)*C_DIM + kk + jj*8], &smem[1][brow*64]);
      }
      __syncthreads();
      bf16x8 aF[4][2], bF[4][2];
      #pragma unroll
      for (int mb = 0; mb < 4; mb++){
        const int row = wr*64 + mb*16 + tl; const int s7 = row & 7;
        aF[mb][0] = as_bf(*(const ushort8*)&smem[0][row*64 + ((g     ^ s7)*8)]);
        aF[mb][1] = as_bf(*(const ushort8*)&smem[0][row*64 + (((4+g) ^ s7)*8)]);
      }
      #pragma unroll
      for (int nb = 0; nb < 4; nb++){
        const int row = wc*64 + nb*16 + tl; const int s7 = row & 7;
        bF[nb][0] = as_bf(*(const ushort8*)&smem[1][row*64 + ((g     ^ s7)*8)]);
        bF[nb][1] = as_bf(*(const ushort8*)&smem[1][row*64 + (((4+g) ^ s7)*8)]);
      }
      #pragma unroll
      for (int mb = 0; mb < 4; mb++)
        #pragma unroll
        for (int nb = 0; nb < 4; nb++){
          acc[mb][nb] = MF(aF[mb][0], bF[nb][0], acc[mb][nb]);
          acc[mb][nb] = MF(aF[mb][1], bF[nb][1], acc[mb][nb]);
        }
    }
    // V epilogue: transpose 128x128 tile through swizzled LDS, write sigma-permuted V^T.
    __syncthreads();
    unsigned short* tr = &smem[0][0];      // 128*128 ushorts = 32 KB
    #pragma unroll
    for (int mb = 0; mb < 4; mb++){
      #pragma unroll
      for (int nb = 0; nb < 4; nb++){
        const int n = wc*64 + nb*16 + tl;
        const int m0 = wr*64 + mb*16 + g*4;
        ushort4e pk;
        #pragma unroll
        for (int r = 0; r < 4; r++) pk[r] = f2b(acc[mb][nb][r]);
        *(ushort4e*)&tr[n*128 + (m0 ^ ((n & 15) << 3))] = pk;
      }
    }
    __syncthreads();
    const int hbase = (nbase - 2048) >> 6;
    const int b = mbase >> 11, tloc = mbase & 2047;
    const int n = tid >> 1, half = tid & 1;
    unsigned short* vdst = vtr + (((size_t)(b*H_NUM + hbase + (n >> 6)))*DHD + (n & 63))*T_SEQ
                           + tloc + half*64;
    const int nx = (n & 15) << 3;
    #pragma unroll
    for (int c8 = 0; c8 < 8; c8++){
      const int t0 = half*64 + (c8 >> 2)*32 + (c8 & 3)*4;
      ushort4e lo = *(const ushort4e*)&tr[n*128 + ((t0     ) ^ nx)];
      ushort4e hi = *(const ushort4e*)&tr[n*128 + ((t0 + 16) ^ nx)];
      ushort8 u;
      #pragma unroll
      for (int e = 0; e < 4; e++){ u[e] = lo[e]; u[4+e] = hi[e]; }
      *(ushort8*)&vdst[c8*8] = u;
    }
  }
}

// ---------------- Flash attention (causal): 8 waves x 32 rows, KVBLK=256 ----------------
// grid 256 (1/CU), in-block pass-pair {bx, 7-bx} (9 staged 256-tiles per pair, balanced).
// Each staged 256-tile runs the proven 128-wide body twice (sub-rounds), ONE barrier/tile.
// P in-register (sigma); V^T global sigma-permuted -> V frag = single b128 read.
__global__ __launch_bounds__(512) void k_flash(const unsigned short* __restrict__ q,
                                               const unsigned short* __restrict__ k,
                                               const unsigned short* __restrict__ vtg,
                                               unsigned short* __restrict__ o){
  __shared__ __align__(16) unsigned short kbufs[2][256*64];   // [s][d]     64 KB
  __shared__ __align__(16) unsigned short vbufs[2][64*256];   // [d][t-loc] 64 KB
  const int tid = threadIdx.x, lane = tid & 63, w = tid >> 6;
  const int g = lane >> 4, tl = lane & 15;
  const int id = blockIdx.x;
  const int swz = (id & 7)*32 + (id >> 3);
  const int bh = swz >> 2, bx = swz & 3;
  const int b = bh >> 4, h = bh & 15;
  const unsigned short* qb = q   + (size_t)bh * T_SEQ * DHD;
  const unsigned short* kb = k   + (size_t)bh * T_SEQ * DHD;
  const unsigned short* vb = vtg + (size_t)bh * (size_t)DHD * T_SEQ;
  const int lrow = lane >> 3, lj = lane & 7;
  const int s7 = tl & 7;
  const int vq = (lane >> 3) & 3;       // V src 64-col quarter

  for (int pass = 0; pass < 2; ++pass){
    const int qt = pass ? (7 - bx) : bx;
    const int tbase = qt * 256;
    const int trow0 = tbase + w * 32;
    const int tmax = trow0 + 31;
    bf16x8 qF[2][2];
    #pragma unroll
    for (int tf = 0; tf < 2; tf++)
      #pragma unroll
      for (int ks = 0; ks < 2; ks++)
        qF[tf][ks] = as_bf(*(const ushort8*)&qb[(size_t)(trow0 + tf*16 + tl)*DHD + ks*32 + g*8]);
    f32x4 acc[2][4] = {};
    float mreg[2] = {-1e30f, -1e30f}, lreg[2] = {0.f, 0.f};
    const int nkt = qt + 1;             // 256-wide kv tiles
    // prologue: stage tile 0 into buf 0 (K: 4 rounds x 8 rows/wave; V: 4 rounds x 2 d-rows/wave)
    #pragma unroll
    for (int i = 0; i < 4; i++){
      const int krow = i*64 + w*8 + lrow;
      gload16(&kb[(size_t)krow*DHD + ((lj ^ (krow & 7))*8)], &kbufs[0][(i*64 + w*8)*64]);
      const int vrow = i*16 + w*2 + (lane >> 5);
      gload16(&vb[(size_t)vrow*T_SEQ + vq*64 + ((lj ^ (vrow & 7))*8)], &vbufs[0][(i*16 + w*2)*256]);
    }
    __syncthreads();
    for (int kti = 0; kti < nkt; ++kti){
      const int cur = kti & 1;
      const int kb256 = kti * 256;
      if (kti + 1 < nkt){
        const int kb2 = kb256 + 256;
        #pragma unroll
        for (int i = 0; i < 4; i++){
          const int krow = i*64 + w*8 + lrow;
          gload16(&kb[(size_t)(kb2+krow)*DHD + ((lj ^ (krow & 7))*8)], &kbufs[cur^1][(i*64 + w*8)*64]);
          const int vrow = i*16 + w*2 + (lane >> 5);
          gload16(&vb[(size_t)vrow*T_SEQ + kb2 + vq*64 + ((lj ^ (vrow & 7))*8)], &vbufs[cur^1][(i*16 + w*2)*256]);
        }
      }
      #pragma unroll
      for (int sh = 0; sh < 2; sh++){
        const int kbase = kb256 + sh*128;
        if (kbase <= tmax){
          const unsigned short* kcur = &kbufs[cur][sh*128*64];
          const unsigned short* vcur = &vbufs[cur][0];
          f32x4 st[2][8] = {};
          __builtin_amdgcn_s_setprio(1);
          #pragma unroll
          for (int sf = 0; sf < 8; sf++){
            const int row = sf*16 + tl;
            const int r7 = row & 7;
            bf16x8 kf0 = as_bf(*(const ushort8*)&kcur[row*64 + ((g     ^ r7)*8)]);
            bf16x8 kf1 = as_bf(*(const ushort8*)&kcur[row*64 + (((4+g) ^ r7)*8)]);
            #pragma unroll
            for (int tf = 0; tf < 2; tf++){
              st[tf][sf] = MF(kf0, qF[tf][0], st[tf][sf]);
              st[tf][sf] = MF(kf1, qF[tf][1], st[tf][sf]);
            }
          }
          __builtin_amdgcn_s_setprio(0);
          if (kbase + 127 > trow0){   // causal mask on near-diagonal sub-tiles
            #pragma unroll
            for (int tf = 0; tf < 2; tf++){
              int tg = trow0 + tf*16 + tl;
              #pragma unroll
              for (int sf = 0; sf < 8; sf++)
                #pragma unroll
                for (int r = 0; r < 4; r++)
                  if (kbase + sf*16 + g*4 + r > tg) st[tf][sf][r] = -1e30f;
            }
          }
          bf16x8 pa[2][4];
          #pragma unroll
          for (int tf = 0; tf < 2; tf++){
            float mloc = -1e30f;
            #pragma unroll
            for (int sf = 0; sf < 8; sf++)
              #pragma unroll
              for (int r = 0; r < 4; r++) mloc = fmaxf(mloc, st[tf][sf][r]);
            if (__any(mloc > mreg[tf] + 8.f)){   // lazy-max (T13)
              float mrow = fmaxf(mloc, __shfl_xor(mloc, 16));
              mrow = fmaxf(mrow, __shfl_xor(mrow, 32));
              float mnew = fmaxf(mreg[tf], mrow);
              float alpha = exp2fast(mreg[tf] - mnew);
              mreg[tf] = mnew;
              lreg[tf] *= alpha;
              #pragma unroll
              for (int df = 0; df < 4; df++)
                #pragma unroll
                for (int r = 0; r < 4; r++) acc[tf][df][r] *= alpha;
            }
            float sum = 0.f;
            #pragma unroll
            for (int q4 = 0; q4 < 4; q4++){
              ushort8 uu;
              #pragma unroll
              for (int r = 0; r < 4; r++){
                float p0 = exp2fast(st[tf][2*q4  ][r] - mreg[tf]);
                float p1 = exp2fast(st[tf][2*q4+1][r] - mreg[tf]);
                sum += p0 + p1;
                uu[r]   = f2b(p0);
                uu[4+r] = f2b(p1);
              }
              pa[tf][q4] = as_bf(uu);
            }
            lreg[tf] += sum;   // per-lane partial; reduced at epilogue
          }
          __builtin_amdgcn_s_setprio(1);
          #pragma unroll
          for (int df = 0; df < 4; df++){
            const int row = df*16 + tl;
            bf16x8 vfr[4];
            #pragma unroll
            for (int q4 = 0; q4 < 4; q4++)
              vfr[q4] = as_bf(*(const ushort8*)&vcur[row*256 + sh*128 + (q4 >> 1)*64 + (((4*(q4 & 1) + g) ^ s7)*8)]);
            #pragma unroll
            for (int tf = 0; tf < 2; tf++)
              #pragma unroll
              for (int q4 = 0; q4 < 4; q4++)
                acc[tf][df] = MF(vfr[q4], pa[tf][q4], acc[tf][df]);
          }
          __builtin_amdgcn_s_setprio(0);
        }
      }
      __syncthreads();
    }
    #pragma unroll
    for (int tf = 0; tf < 2; tf++){
      float l = lreg[tf];
      l += __shfl_xor(l, 16);
      l += __shfl_xor(l, 32);
      float inv = 1.f / l;
      int tg = trow0 + tf*16 + tl;
      #pragma unroll
      for (int df = 0; df < 4; df++){
        ushort4e ov;
        #pragma unroll
        for (int r = 0; r < 4; r++) ov[r] = f2b(acc[tf][df][r] * inv);
        *(ushort4e*)&o[((size_t)(b*T_SEQ + tg))*C_DIM + h*DHD + df*16 + g*4] = ov;
      }
    }
  }
}

// ---------------- GEMM: output projection + bias (128-tile m97 structure) ----------------
__global__ __launch_bounds__(256) void k_gemm_proj(const unsigned short* __restrict__ ab,
                                                   const unsigned short* __restrict__ wot,
                                                   const float* __restrict__ bo,
                                                   float* __restrict__ out){
  __shared__ __align__(16) unsigned short a_lds[128*64];
  __shared__ __align__(16) unsigned short b_lds[128*64];
  const int tid = threadIdx.x, lane = tid & 63, wid = tid >> 6;
  const int g = lane >> 4, tl = lane & 15;
  const int wr = wid >> 1, wc = wid & 1;
  const int id = blockIdx.x;
  const int swz = (id & 7)*64 + (id >> 3);
  const int mbase = (swz >> 3) * 128, nbase = (swz & 7) * 128;
  f32x4 acc[4][4] = {};
  for (int kk = 0; kk < C_DIM; kk += 64){
    __syncthreads();
    #pragma unroll
    for (int i = 0; i < 4; i++){
      const int brow = (wid*4 + i)*8;
      const int row  = brow + (lane >> 3);
      const int jj   = (lane & 7) ^ (row & 7);
      gload16(&ab[(size_t)(mbase+row)*C_DIM + kk + jj*8],  &a_lds[brow*64]);
      gload16(&wot[(size_t)(nbase+row)*C_DIM + kk + jj*8], &b_lds[brow*64]);
    }
    __syncthreads();
    bf16x8 aF[4][2], bF[4][2];
    #pragma unroll
    for (int mb = 0; mb < 4; mb++){
      const int row = wr*64 + mb*16 + tl; const int s7 = row & 7;
      aF[mb][0] = as_bf(*(const ushort8*)&a_lds[row*64 + ((g     ^ s7)*8)]);
      aF[mb][1] = as_bf(*(const ushort8*)&a_lds[row*64 + (((4+g) ^ s7)*8)]);
    }
    #pragma unroll
    for (int nb = 0; nb < 4; nb++){
      const int row = wc*64 + nb*16 + tl; const int s7 = row & 7;
      bF[nb][0] = as_bf(*(const ushort8*)&b_lds[row*64 + ((g     ^ s7)*8)]);
      bF[nb][1] = as_bf(*(const ushort8*)&b_lds[row*64 + (((4+g) ^ s7)*8)]);
    }
    #pragma unroll
    for (int mb = 0; mb < 4; mb++)
      #pragma unroll
      for (int nb = 0; nb < 4; nb++){
        acc[mb][nb] = MF(aF[mb][0], bF[nb][0], acc[mb][nb]);
        acc[mb][nb] = MF(aF[mb][1], bF[nb][1], acc[mb][nb]);
      }
  }
  #pragma unroll
  for (int mb = 0; mb < 4; mb++){
    #pragma unroll
    for (int nb = 0; nb < 4; nb++){
      #pragma unroll
      for (int r = 0; r < 4; r++){
        int gr = mbase + wr*64 + mb*16 + g*4 + r;
        int gc = nbase + wc*64 + nb*16 + tl;
        out[(size_t)gr*C_DIM + gc] = acc[mb][nb][r] + bo[gc];
      }
    }
  }
}

extern "C" void kernel_launch(void* const* d_in, const int* in_sizes, int n_in,
                              void* d_out, int out_size, void* d_ws, size_t ws_size,
                              hipStream_t stream){
  const float* x  = (const float*)d_in[0];
  const float* Wq = (const float*)d_in[1];
  const float* Wk = (const float*)d_in[2];
  const float* Wv = (const float*)d_in[3];
  const float* Wo = (const float*)d_in[4];
  const float* bo = (const float*)d_in[5];
  float* out = (float*)d_out;

  char* p = (char*)d_ws;
  unsigned short* xb  = (unsigned short*)p; p += (size_t)M_ROWS*C_DIM*2;   // 16MB
  unsigned short* wt  = (unsigned short*)p; p += (size_t)3*C_DIM*C_DIM*2;  // 6MB
  unsigned short* wot = (unsigned short*)p; p += (size_t)C_DIM*C_DIM*2;    // 2MB
  unsigned short* Qb  = (unsigned short*)p; p += (size_t)M_ROWS*C_DIM*2;   // 16MB
  unsigned short* Kb  = (unsigned short*)p; p += (size_t)M_ROWS*C_DIM*2;   // 16MB
  unsigned short* Vtr = (unsigned short*)p; p += (size_t)M_ROWS*C_DIM*2;   // 16MB (sigma-permuted V^T)
  unsigned short* attn = xb;   // reuse: xb dead after k_gemm_qkv

  hipLaunchKernelGGL(k_prep, dim3(8192 + 1024), dim3(256), 0, stream,
                     x, Wq, Wk, Wv, Wo, xb, wt, wot);
  hipLaunchKernelGGL(k_gemm_qkv, dim3(1536), dim3(256), 0, stream,
                     xb, wt, Qb, Kb, Vtr);
  hipLaunchKernelGGL(k_flash, dim3(256), dim3(512), 0, stream,
                     Qb, Kb, Vtr, attn);
  hipLaunchKernelGGL(k_gemm_proj, dim3(512), dim3(256), 0, stream,
                     attn, wot, bo, out);
}

// Round 23
// 159.989 us; speedup vs baseline: 1.0232x; 1.0186x over previous
//
#include <hip/hip_runtime.h>

// MHA fused forward: B=4, T=2048, C=1024, H=16, DH=64
#define T_SEQ 2048
#define C_DIM 1024
#define H_NUM 16
#define DHD   64
#define B_NUM 4
#define M_ROWS (B_NUM*T_SEQ)   // 8192

typedef __bf16 bf16x8 __attribute__((ext_vector_type(8)));
typedef float  f32x4  __attribute__((ext_vector_type(4)));
typedef unsigned short ushort8 __attribute__((ext_vector_type(8)));
typedef unsigned short ushort4e __attribute__((ext_vector_type(4)));

__device__ __forceinline__ unsigned short f2b(float f){
  return __builtin_bit_cast(unsigned short, (__bf16)f);
}
__device__ __forceinline__ bf16x8 as_bf(ushort8 u){ return __builtin_bit_cast(bf16x8, u); }
__device__ __forceinline__ float exp2fast(float x){ return __builtin_amdgcn_exp2f(x); }

__device__ __forceinline__ void gload16(const void* g, void* l){
  __builtin_amdgcn_global_load_lds(
      (const __attribute__((address_space(1))) void*)g,
      (__attribute__((address_space(3))) void*)l, 16, 0, 0);
}

#define MF(a,b,c) __builtin_amdgcn_mfma_f32_16x16x32_bf16(a,b,c,0,0,0)

// ---------------- prep: x f32->bf16 + coalesced weight pack (LDS transpose) ----------------
__global__ __launch_bounds__(256) void k_prep(const float* __restrict__ x,
                                              const float* __restrict__ wq,
                                              const float* __restrict__ wk,
                                              const float* __restrict__ wv,
                                              const float* __restrict__ wo,
                                              unsigned short* __restrict__ xb,
                                              unsigned short* __restrict__ wt,
                                              unsigned short* __restrict__ wot){
  const int bid = blockIdx.x;
  const int tid = threadIdx.x;
  if (bid < 8192){
    int i = bid*256 + tid;
    float4 f = ((const float4*)x)[i];
    ushort4e o;
    o[0]=f2b(f.x); o[1]=f2b(f.y); o[2]=f2b(f.z); o[3]=f2b(f.w);
    ((ushort4e*)xb)[i] = o;
    return;
  }
  __shared__ __align__(16) unsigned short vr[64][72];
  const int tb = bid - 8192;
  const float* S; int LS; unsigned short* D; int R0, C0; float scale = 1.f;
  if (tb < 768){
    int m = tb >> 8, rem = tb & 255;
    int h = rem >> 4, c0 = rem & 15;
    S = ((m==0)?wq:(m==1)?wk:wv) + (size_t)(h*16 + c0)*64*64;
    LS = 64;
    D = wt; R0 = m*1024 + h*64; C0 = c0*64;
    if (m == 0) scale = 0.125f * 1.4426950408889634f;  // DH^-0.5 * log2(e)
  } else {
    int tb2 = tb - 768;
    int nb = tb2 >> 4, cb = tb2 & 15;
    S = wo + (size_t)(cb*64)*1024 + nb*64;
    LS = 1024;
    D = wot; R0 = nb*64; C0 = cb*64;
  }
  #pragma unroll
  for (int i = 0; i < 2; i++){
    int id2 = tid + i*256;
    int r = id2 >> 3, e8 = (id2 & 7)*8;
    float4 a = *(const float4*)&S[(size_t)r*LS + e8];
    float4 b2 = *(const float4*)&S[(size_t)r*LS + e8 + 4];
    ushort8 u;
    u[0]=f2b(a.x*scale); u[1]=f2b(a.y*scale); u[2]=f2b(a.z*scale); u[3]=f2b(a.w*scale);
    u[4]=f2b(b2.x*scale); u[5]=f2b(b2.y*scale); u[6]=f2b(b2.z*scale); u[7]=f2b(b2.w*scale);
    *(ushort8*)&vr[r][e8 ^ ((r >> 3) << 3)] = u;
  }
  __syncthreads();
  #pragma unroll
  for (int i = 0; i < 2; i++){
    int id2 = tid + i*256;
    int d = id2 >> 3, oc = id2 & 7;
    ushort8 u;
    #pragma unroll
    for (int j = 0; j < 8; j++)
      u[j] = vr[oc*8 + j][d ^ (oc << 3)];
    *(ushort8*)&D[(size_t)(R0 + d)*1024 + C0 + oc*8] = u;
  }
}

// ---------------- GEMM: QKV projection (1-barrier stage-ahead double-buffer) ----------------
// Per K-step: stage(next tile -> buf^1) issued FIRST, then frag-reads+MFMA on buf, then
// ONE __syncthreads() (its vmcnt drain overlaps the compute). Q/K blocks compute C^T
// (swapped MFMA) -> ushort4 stores; V blocks keep orientation + sigma-permuted V^T epilogue.
__global__ __launch_bounds__(256) void k_gemm_qkv(const unsigned short* __restrict__ xb,
                                                  const unsigned short* __restrict__ wt,
                                                  unsigned short* __restrict__ qo,
                                                  unsigned short* __restrict__ ko,
                                                  unsigned short* __restrict__ vtr){
  __shared__ __align__(16) unsigned short smem[4][128*64];   // A:[0,1]  B:[2,3]  (64 KB)
  const int tid = threadIdx.x, lane = tid & 63, wid = tid >> 6;
  const int g = lane >> 4, tl = lane & 15;
  const int wr = wid >> 1, wc = wid & 1;
  const int id = blockIdx.x;
  const int xcd = id & 7, i = id >> 3;        // 192 blocks per XCD
  const int xm = xcd >> 1, xn = xcd & 1;
  const int mbase = (xm*16 + i/12) * 128, nbase = (xn*12 + i%12) * 128;
  const int sel = nbase >> 10;   // block-uniform
  const int srow8 = lane >> 3, sj = lane & 7;
  f32x4 acc[4][4] = {};

#define QKV_STAGE(BUF, KK) do{                                                  \
    _Pragma("unroll")                                                           \
    for (int i2 = 0; i2 < 4; i2++){                                             \
      const int brow = (wid*4 + i2)*8;                                          \
      const int row  = brow + srow8;                                            \
      const int jj   = sj ^ (row & 7);                                          \
      gload16(&xb[(size_t)(mbase+row)*C_DIM + (KK) + jj*8], &smem[BUF][brow*64]);   \
      gload16(&wt[(size_t)(nbase+row)*C_DIM + (KK) + jj*8], &smem[2+(BUF)][brow*64]);\
    }                                                                           \
  }while(0)

#define QKV_FRAGS(BUF)                                                          \
    bf16x8 aF[4][2], bF[4][2];                                                  \
    _Pragma("unroll")                                                           \
    for (int mb = 0; mb < 4; mb++){                                             \
      const int row = wr*64 + mb*16 + tl; const int s7 = row & 7;               \
      aF[mb][0] = as_bf(*(const ushort8*)&smem[BUF][row*64 + ((g     ^ s7)*8)]);\
      aF[mb][1] = as_bf(*(const ushort8*)&smem[BUF][row*64 + (((4+g) ^ s7)*8)]);\
    }                                                                           \
    _Pragma("unroll")                                                           \
    for (int nb = 0; nb < 4; nb++){                                             \
      const int row = wc*64 + nb*16 + tl; const int s7 = row & 7;               \
      bF[nb][0] = as_bf(*(const ushort8*)&smem[2+(BUF)][row*64 + ((g     ^ s7)*8)]);\
      bF[nb][1] = as_bf(*(const ushort8*)&smem[2+(BUF)][row*64 + (((4+g) ^ s7)*8)]);\
    }

  if (sel < 2){
    QKV_STAGE(0, 0);
    __syncthreads();
    #pragma unroll 1
    for (int it = 0; it < 16; ++it){
      const int cur = it & 1;
      if (it + 1 < 16) QKV_STAGE(cur^1, (it+1)*64);
      QKV_FRAGS(cur);
      #pragma unroll
      for (int mb = 0; mb < 4; mb++)
        #pragma unroll
        for (int nb = 0; nb < 4; nb++){
          acc[mb][nb] = MF(bF[nb][0], aF[mb][0], acc[mb][nb]);   // swapped: C^T
          acc[mb][nb] = MF(bF[nb][1], aF[mb][1], acc[mb][nb]);
        }
      __syncthreads();
    }
    unsigned short* dst0 = (sel == 0) ? qo : ko;
    const int nloc = (nbase & 1023) + wc*64;
    #pragma unroll
    for (int mb = 0; mb < 4; mb++){
      const int t = mbase + wr*64 + mb*16 + tl;
      const int b = t >> 11, tt = t & 2047;
      #pragma unroll
      for (int nb = 0; nb < 4; nb++){
        const int nw = nloc + nb*16 + g*4;
        const int h = nw >> 6, d0 = nw & 63;
        ushort4e pk;
        #pragma unroll
        for (int r = 0; r < 4; r++) pk[r] = f2b(acc[mb][nb][r]);
        *(ushort4e*)&dst0[(((size_t)(b*H_NUM + h))*T_SEQ + tt)*DHD + d0] = pk;
      }
    }
  } else {
    QKV_STAGE(0, 0);
    __syncthreads();
    #pragma unroll 1
    for (int it = 0; it < 16; ++it){
      const int cur = it & 1;
      if (it + 1 < 16) QKV_STAGE(cur^1, (it+1)*64);
      QKV_FRAGS(cur);
      #pragma unroll
      for (int mb = 0; mb < 4; mb++)
        #pragma unroll
        for (int nb = 0; nb < 4; nb++){
          acc[mb][nb] = MF(aF[mb][0], bF[nb][0], acc[mb][nb]);
          acc[mb][nb] = MF(aF[mb][1], bF[nb][1], acc[mb][nb]);
        }
      __syncthreads();
    }
    // V epilogue: transpose 128x128 tile through swizzled LDS, write sigma-permuted V^T.
    unsigned short* tr = &smem[0][0];      // 128*128 ushorts = 32 KB (aliases A bufs)
    #pragma unroll
    for (int mb = 0; mb < 4; mb++){
      #pragma unroll
      for (int nb = 0; nb < 4; nb++){
        const int n = wc*64 + nb*16 + tl;
        const int m0 = wr*64 + mb*16 + g*4;
        ushort4e pk;
        #pragma unroll
        for (int r = 0; r < 4; r++) pk[r] = f2b(acc[mb][nb][r]);
        *(ushort4e*)&tr[n*128 + (m0 ^ ((n & 15) << 3))] = pk;
      }
    }
    __syncthreads();
    const int hbase = (nbase - 2048) >> 6;
    const int b = mbase >> 11, tloc = mbase & 2047;
    const int n = tid >> 1, half = tid & 1;
    unsigned short* vdst = vtr + (((size_t)(b*H_NUM + hbase + (n >> 6)))*DHD + (n & 63))*T_SEQ
                           + tloc + half*64;
    const int nx = (n & 15) << 3;
    #pragma unroll
    for (int c8 = 0; c8 < 8; c8++){
      const int t0 = half*64 + (c8 >> 2)*32 + (c8 & 3)*4;
      ushort4e lo = *(const ushort4e*)&tr[n*128 + ((t0     ) ^ nx)];
      ushort4e hi = *(const ushort4e*)&tr[n*128 + ((t0 + 16) ^ nx)];
      ushort8 u;
      #pragma unroll
      for (int e = 0; e < 4; e++){ u[e] = lo[e]; u[4+e] = hi[e]; }
      *(ushort8*)&vdst[c8*8] = u;
    }
  }
#undef QKV_STAGE
#undef QKV_FRAGS
}

// ---------------- Flash attention (causal): 8 waves x 32 rows, KVBLK=256 ----------------
// grid 256 (1/CU), in-block pass-pair {bx, 7-bx}. One barrier per staged 256-tile.
// P in-register (sigma); V^T global sigma-permuted -> V frag = single b128 read.
__global__ __launch_bounds__(512) void k_flash(const unsigned short* __restrict__ q,
                                               const unsigned short* __restrict__ k,
                                               const unsigned short* __restrict__ vtg,
                                               unsigned short* __restrict__ o){
  __shared__ __align__(16) unsigned short kbufs[2][256*64];   // [s][d]     64 KB
  __shared__ __align__(16) unsigned short vbufs[2][64*256];   // [d][t-loc] 64 KB
  const int tid = threadIdx.x, lane = tid & 63, w = tid >> 6;
  const int g = lane >> 4, tl = lane & 15;
  const int id = blockIdx.x;
  const int swz = (id & 7)*32 + (id >> 3);
  const int bh = swz >> 2, bx = swz & 3;
  const int b = bh >> 4, h = bh & 15;
  const unsigned short* qb = q   + (size_t)bh * T_SEQ * DHD;
  const unsigned short* kb = k   + (size_t)bh * T_SEQ * DHD;
  const unsigned short* vb = vtg + (size_t)bh * (size_t)DHD * T_SEQ;
  const int lrow = lane >> 3, lj = lane & 7;
  const int s7 = tl & 7;
  const int vq = (lane >> 3) & 3;       // V src 64-col quarter

  for (int pass = 0; pass < 2; ++pass){
    const int qt = pass ? (7 - bx) : bx;
    const int tbase = qt * 256;
    const int trow0 = tbase + w * 32;
    const int tmax = trow0 + 31;
    bf16x8 qF[2][2];
    #pragma unroll
    for (int tf = 0; tf < 2; tf++)
      #pragma unroll
      for (int ks = 0; ks < 2; ks++)
        qF[tf][ks] = as_bf(*(const ushort8*)&qb[(size_t)(trow0 + tf*16 + tl)*DHD + ks*32 + g*8]);
    f32x4 acc[2][4] = {};
    float mreg[2] = {-1e30f, -1e30f}, lreg[2] = {0.f, 0.f};
    const int nkt = qt + 1;             // 256-wide kv tiles
    #pragma unroll
    for (int i = 0; i < 4; i++){
      const int krow = i*64 + w*8 + lrow;
      gload16(&kb[(size_t)krow*DHD + ((lj ^ (krow & 7))*8)], &kbufs[0][(i*64 + w*8)*64]);
      const int vrow = i*16 + w*2 + (lane >> 5);
      gload16(&vb[(size_t)vrow*T_SEQ + vq*64 + ((lj ^ (vrow & 7))*8)], &vbufs[0][(i*16 + w*2)*256]);
    }
    __syncthreads();
    for (int kti = 0; kti < nkt; ++kti){
      const int cur = kti & 1;
      const int kb256 = kti * 256;
      if (kti + 1 < nkt){
        const int kb2 = kb256 + 256;
        #pragma unroll
        for (int i = 0; i < 4; i++){
          const int krow = i*64 + w*8 + lrow;
          gload16(&kb[(size_t)(kb2+krow)*DHD + ((lj ^ (krow & 7))*8)], &kbufs[cur^1][(i*64 + w*8)*64]);
          const int vrow = i*16 + w*2 + (lane >> 5);
          gload16(&vb[(size_t)vrow*T_SEQ + kb2 + vq*64 + ((lj ^ (vrow & 7))*8)], &vbufs[cur^1][(i*16 + w*2)*256]);
        }
      }
      #pragma unroll
      for (int sh = 0; sh < 2; sh++){
        const int kbase = kb256 + sh*128;
        if (kbase <= tmax){
          const unsigned short* kcur = &kbufs[cur][sh*128*64];
          const unsigned short* vcur = &vbufs[cur][0];
          f32x4 st[2][8] = {};
          __builtin_amdgcn_s_setprio(1);
          #pragma unroll
          for (int sf = 0; sf < 8; sf++){
            const int row = sf*16 + tl;
            const int r7 = row & 7;
            bf16x8 kf0 = as_bf(*(const ushort8*)&kcur[row*64 + ((g     ^ r7)*8)]);
            bf16x8 kf1 = as_bf(*(const ushort8*)&kcur[row*64 + (((4+g) ^ r7)*8)]);
            #pragma unroll
            for (int tf = 0; tf < 2; tf++){
              st[tf][sf] = MF(kf0, qF[tf][0], st[tf][sf]);
              st[tf][sf] = MF(kf1, qF[tf][1], st[tf][sf]);
            }
          }
          __builtin_amdgcn_s_setprio(0);
          if (kbase + 127 > trow0){   // causal mask on near-diagonal sub-tiles
            #pragma unroll
            for (int tf = 0; tf < 2; tf++){
              int tg = trow0 + tf*16 + tl;
              #pragma unroll
              for (int sf = 0; sf < 8; sf++)
                #pragma unroll
                for (int r = 0; r < 4; r++)
                  if (kbase + sf*16 + g*4 + r > tg) st[tf][sf][r] = -1e30f;
            }
          }
          bf16x8 pa[2][4];
          #pragma unroll
          for (int tf = 0; tf < 2; tf++){
            float mloc = -1e30f;
            #pragma unroll
            for (int sf = 0; sf < 8; sf++)
              #pragma unroll
              for (int r = 0; r < 4; r++) mloc = fmaxf(mloc, st[tf][sf][r]);
            if (__any(mloc > mreg[tf] + 8.f)){   // lazy-max (T13)
              float mrow = fmaxf(mloc, __shfl_xor(mloc, 16));
              mrow = fmaxf(mrow, __shfl_xor(mrow, 32));
              float mnew = fmaxf(mreg[tf], mrow);
              float alpha = exp2fast(mreg[tf] - mnew);
              mreg[tf] = mnew;
              lreg[tf] *= alpha;
              #pragma unroll
              for (int df = 0; df < 4; df++)
                #pragma unroll
                for (int r = 0; r < 4; r++) acc[tf][df][r] *= alpha;
            }
            float sum = 0.f;
            #pragma unroll
            for (int q4 = 0; q4 < 4; q4++){
              ushort8 uu;
              #pragma unroll
              for (int r = 0; r < 4; r++){
                float p0 = exp2fast(st[tf][2*q4  ][r] - mreg[tf]);
                float p1 = exp2fast(st[tf][2*q4+1][r] - mreg[tf]);
                sum += p0 + p1;
                uu[r]   = f2b(p0);
                uu[4+r] = f2b(p1);
              }
              pa[tf][q4] = as_bf(uu);
            }
            lreg[tf] += sum;   // per-lane partial; reduced at epilogue
          }
          __builtin_amdgcn_s_setprio(1);
          #pragma unroll
          for (int df = 0; df < 4; df++){
            const int row = df*16 + tl;
            bf16x8 vfr[4];
            #pragma unroll
            for (int q4 = 0; q4 < 4; q4++)
              vfr[q4] = as_bf(*(const ushort8*)&vcur[row*256 + sh*128 + (q4 >> 1)*64 + (((4*(q4 & 1) + g) ^ s7)*8)]);
            #pragma unroll
            for (int tf = 0; tf < 2; tf++)
              #pragma unroll
              for (int q4 = 0; q4 < 4; q4++)
                acc[tf][df] = MF(vfr[q4], pa[tf][q4], acc[tf][df]);
          }
          __builtin_amdgcn_s_setprio(0);
        }
      }
      __syncthreads();
    }
    #pragma unroll
    for (int tf = 0; tf < 2; tf++){
      float l = lreg[tf];
      l += __shfl_xor(l, 16);
      l += __shfl_xor(l, 32);
      float inv = 1.f / l;
      int tg = trow0 + tf*16 + tl;
      #pragma unroll
      for (int df = 0; df < 4; df++){
        ushort4e ov;
        #pragma unroll
        for (int r = 0; r < 4; r++) ov[r] = f2b(acc[tf][df][r] * inv);
        *(ushort4e*)&o[((size_t)(b*T_SEQ + tg))*C_DIM + h*DHD + df*16 + g*4] = ov;
      }
    }
  }
}

// ---------------- GEMM: output projection + bias (128-tile m97 structure) ----------------
__global__ __launch_bounds__(256) void k_gemm_proj(const unsigned short* __restrict__ ab,
                                                   const unsigned short* __restrict__ wot,
                                                   const float* __restrict__ bo,
                                                   float* __restrict__ out){
  __shared__ __align__(16) unsigned short a_lds[128*64];
  __shared__ __align__(16) unsigned short b_lds[128*64];
  const int tid = threadIdx.x, lane = tid & 63, wid = tid >> 6;
  const int g = lane >> 4, tl = lane & 15;
  const int wr = wid >> 1, wc = wid & 1;
  const int id = blockIdx.x;
  const int swz = (id & 7)*64 + (id >> 3);
  const int mbase = (swz >> 3) * 128, nbase = (swz & 7) * 128;
  f32x4 acc[4][4] = {};
  for (int kk = 0; kk < C_DIM; kk += 64){
    __syncthreads();
    #pragma unroll
    for (int i = 0; i < 4; i++){
      const int brow = (wid*4 + i)*8;
      const int row  = brow + (lane >> 3);
      const int jj   = (lane & 7) ^ (row & 7);
      gload16(&ab[(size_t)(mbase+row)*C_DIM + kk + jj*8],  &a_lds[brow*64]);
      gload16(&wot[(size_t)(nbase+row)*C_DIM + kk + jj*8], &b_lds[brow*64]);
    }
    __syncthreads();
    bf16x8 aF[4][2], bF[4][2];
    #pragma unroll
    for (int mb = 0; mb < 4; mb++){
      const int row = wr*64 + mb*16 + tl; const int s7 = row & 7;
      aF[mb][0] = as_bf(*(const ushort8*)&a_lds[row*64 + ((g     ^ s7)*8)]);
      aF[mb][1] = as_bf(*(const ushort8*)&a_lds[row*64 + (((4+g) ^ s7)*8)]);
    }
    #pragma unroll
    for (int nb = 0; nb < 4; nb++){
      const int row = wc*64 + nb*16 + tl; const int s7 = row & 7;
      bF[nb][0] = as_bf(*(const ushort8*)&b_lds[row*64 + ((g     ^ s7)*8)]);
      bF[nb][1] = as_bf(*(const ushort8*)&b_lds[row*64 + (((4+g) ^ s7)*8)]);
    }
    #pragma unroll
    for (int mb = 0; mb < 4; mb++)
      #pragma unroll
      for (int nb = 0; nb < 4; nb++){
        acc[mb][nb] = MF(aF[mb][0], bF[nb][0], acc[mb][nb]);
        acc[mb][nb] = MF(aF[mb][1], bF[nb][1], acc[mb][nb]);
      }
  }
  #pragma unroll
  for (int mb = 0; mb < 4; mb++){
    #pragma unroll
    for (int nb = 0; nb < 4; nb++){
      #pragma unroll
      for (int r = 0; r < 4; r++){
        int gr = mbase + wr*64 + mb*16 + g*4 + r;
        int gc = nbase + wc*64 + nb*16 + tl;
        out[(size_t)gr*C_DIM + gc] = acc[mb][nb][r] + bo[gc];
      }
    }
  }
}

extern "C" void kernel_launch(void* const* d_in, const int* in_sizes, int n_in,
                              void* d_out, int out_size, void* d_ws, size_t ws_size,
                              hipStream_t stream){
  const float* x  = (const float*)d_in[0];
  const float* Wq = (const float*)d_in[1];
  const float* Wk = (const float*)d_in[2];
  const float* Wv = (const float*)d_in[3];
  const float* Wo = (const float*)d_in[4];
  const float* bo = (const float*)d_in[5];
  float* out = (float*)d_out;

  char* p = (char*)d_ws;
  unsigned short* xb  = (unsigned short*)p; p += (size_t)M_ROWS*C_DIM*2;   // 16MB
  unsigned short* wt  = (unsigned short*)p; p += (size_t)3*C_DIM*C_DIM*2;  // 6MB
  unsigned short* wot = (unsigned short*)p; p += (size_t)C_DIM*C_DIM*2;    // 2MB
  unsigned short* Qb  = (unsigned short*)p; p += (size_t)M_ROWS*C_DIM*2;   // 16MB
  unsigned short* Kb  = (unsigned short*)p; p += (size_t)M_ROWS*C_DIM*2;   // 16MB
  unsigned short* Vtr = (unsigned short*)p; p += (size_t)M_ROWS*C_DIM*2;   // 16MB (sigma-permuted V^T)
  unsigned short* attn = xb;   // reuse: xb dead after k_gemm_qkv

  hipLaunchKernelGGL(k_prep, dim3(8192 + 1024), dim3(256), 0, stream,
                     x, Wq, Wk, Wv, Wo, xb, wt, wot);
  hipLaunchKernelGGL(k_gemm_qkv, dim3(1536), dim3(256), 0, stream,
                     xb, wt, Qb, Kb, Vtr);
  hipLaunchKernelGGL(k_flash, dim3(256), dim3(512), 0, stream,
                     Qb, Kb, Vtr, attn);
  hipLaunchKernelGGL(k_gemm_proj, dim3(512), dim3(256), 0, stream,
                     attn, wot, bo, out);
}

// Round 24
// 156.914 us; speedup vs baseline: 1.0432x; 1.0196x over previous
//
#include <hip/hip_runtime.h>

// MHA fused forward: B=4, T=2048, C=1024, H=16, DH=64
#define T_SEQ 2048
#define C_DIM 1024
#define H_NUM 16
#define DHD   64
#define B_NUM 4
#define M_ROWS (B_NUM*T_SEQ)   // 8192

typedef __bf16 bf16x8 __attribute__((ext_vector_type(8)));
typedef float  f32x4  __attribute__((ext_vector_type(4)));
typedef unsigned short ushort8 __attribute__((ext_vector_type(8)));
typedef unsigned short ushort4e __attribute__((ext_vector_type(4)));

__device__ __forceinline__ unsigned short f2b(float f){
  return __builtin_bit_cast(unsigned short, (__bf16)f);
}
__device__ __forceinline__ bf16x8 as_bf(ushort8 u){ return __builtin_bit_cast(bf16x8, u); }
__device__ __forceinline__ float exp2fast(float x){ return __builtin_amdgcn_exp2f(x); }

__device__ __forceinline__ void gload16(const void* g, void* l){
  __builtin_amdgcn_global_load_lds(
      (const __attribute__((address_space(1))) void*)g,
      (__attribute__((address_space(3))) void*)l, 16, 0, 0);
}

#define MF(a,b,c) __builtin_amdgcn_mfma_f32_16x16x32_bf16(a,b,c,0,0,0)

// ---------------- prep: x f32->bf16 + coalesced weight pack (LDS transpose) ----------------
__global__ __launch_bounds__(256) void k_prep(const float* __restrict__ x,
                                              const float* __restrict__ wq,
                                              const float* __restrict__ wk,
                                              const float* __restrict__ wv,
                                              const float* __restrict__ wo,
                                              unsigned short* __restrict__ xb,
                                              unsigned short* __restrict__ wt,
                                              unsigned short* __restrict__ wot){
  const int bid = blockIdx.x;
  const int tid = threadIdx.x;
  if (bid < 8192){
    int i = bid*256 + tid;
    float4 f = ((const float4*)x)[i];
    ushort4e o;
    o[0]=f2b(f.x); o[1]=f2b(f.y); o[2]=f2b(f.z); o[3]=f2b(f.w);
    ((ushort4e*)xb)[i] = o;
    return;
  }
  __shared__ __align__(16) unsigned short vr[64][72];
  const int tb = bid - 8192;
  const float* S; int LS; unsigned short* D; int R0, C0; float scale = 1.f;
  if (tb < 768){
    int m = tb >> 8, rem = tb & 255;
    int h = rem >> 4, c0 = rem & 15;
    S = ((m==0)?wq:(m==1)?wk:wv) + (size_t)(h*16 + c0)*64*64;
    LS = 64;
    D = wt; R0 = m*1024 + h*64; C0 = c0*64;
    if (m == 0) scale = 0.125f * 1.4426950408889634f;  // DH^-0.5 * log2(e)
  } else {
    int tb2 = tb - 768;
    int nb = tb2 >> 4, cb = tb2 & 15;
    S = wo + (size_t)(cb*64)*1024 + nb*64;
    LS = 1024;
    D = wot; R0 = nb*64; C0 = cb*64;
  }
  #pragma unroll
  for (int i = 0; i < 2; i++){
    int id2 = tid + i*256;
    int r = id2 >> 3, e8 = (id2 & 7)*8;
    float4 a = *(const float4*)&S[(size_t)r*LS + e8];
    float4 b2 = *(const float4*)&S[(size_t)r*LS + e8 + 4];
    ushort8 u;
    u[0]=f2b(a.x*scale); u[1]=f2b(a.y*scale); u[2]=f2b(a.z*scale); u[3]=f2b(a.w*scale);
    u[4]=f2b(b2.x*scale); u[5]=f2b(b2.y*scale); u[6]=f2b(b2.z*scale); u[7]=f2b(b2.w*scale);
    *(ushort8*)&vr[r][e8 ^ ((r >> 3) << 3)] = u;
  }
  __syncthreads();
  #pragma unroll
  for (int i = 0; i < 2; i++){
    int id2 = tid + i*256;
    int d = id2 >> 3, oc = id2 & 7;
    ushort8 u;
    #pragma unroll
    for (int j = 0; j < 8; j++)
      u[j] = vr[oc*8 + j][d ^ (oc << 3)];
    *(ushort8*)&D[(size_t)(R0 + d)*1024 + C0 + oc*8] = u;
  }
}

// ---------------- GEMM: QKV projection (1-barrier stage-ahead double-buffer) ----------------
// Per K-step: stage(next tile -> buf^1) issued FIRST, then frag-reads+MFMA on buf, then
// ONE __syncthreads() (its vmcnt drain overlaps the compute). Q/K blocks compute C^T
// (swapped MFMA) -> ushort4 stores; V blocks keep orientation + sigma-permuted V^T epilogue.
__global__ __launch_bounds__(256) void k_gemm_qkv(const unsigned short* __restrict__ xb,
                                                  const unsigned short* __restrict__ wt,
                                                  unsigned short* __restrict__ qo,
                                                  unsigned short* __restrict__ ko,
                                                  unsigned short* __restrict__ vtr){
  __shared__ __align__(16) unsigned short smem[4][128*64];   // A:[0,1]  B:[2,3]  (64 KB)
  const int tid = threadIdx.x, lane = tid & 63, wid = tid >> 6;
  const int g = lane >> 4, tl = lane & 15;
  const int wr = wid >> 1, wc = wid & 1;
  const int id = blockIdx.x;
  const int xcd = id & 7, i = id >> 3;        // 192 blocks per XCD
  const int xm = xcd >> 1, xn = xcd & 1;
  const int mbase = (xm*16 + i/12) * 128, nbase = (xn*12 + i%12) * 128;
  const int sel = nbase >> 10;   // block-uniform
  const int srow8 = lane >> 3, sj = lane & 7;
  f32x4 acc[4][4] = {};

#define QKV_STAGE(BUF, KK) do{                                                  \
    _Pragma("unroll")                                                           \
    for (int i2 = 0; i2 < 4; i2++){                                             \
      const int brow = (wid*4 + i2)*8;                                          \
      const int row  = brow + srow8;                                            \
      const int jj   = sj ^ (row & 7);                                          \
      gload16(&xb[(size_t)(mbase+row)*C_DIM + (KK) + jj*8], &smem[BUF][brow*64]);   \
      gload16(&wt[(size_t)(nbase+row)*C_DIM + (KK) + jj*8], &smem[2+(BUF)][brow*64]);\
    }                                                                           \
  }while(0)

#define QKV_FRAGS(BUF)                                                          \
    bf16x8 aF[4][2], bF[4][2];                                                  \
    _Pragma("unroll")                                                           \
    for (int mb = 0; mb < 4; mb++){                                             \
      const int row = wr*64 + mb*16 + tl; const int s7 = row & 7;               \
      aF[mb][0] = as_bf(*(const ushort8*)&smem[BUF][row*64 + ((g     ^ s7)*8)]);\
      aF[mb][1] = as_bf(*(const ushort8*)&smem[BUF][row*64 + (((4+g) ^ s7)*8)]);\
    }                                                                           \
    _Pragma("unroll")                                                           \
    for (int nb = 0; nb < 4; nb++){                                             \
      const int row = wc*64 + nb*16 + tl; const int s7 = row & 7;               \
      bF[nb][0] = as_bf(*(const ushort8*)&smem[2+(BUF)][row*64 + ((g     ^ s7)*8)]);\
      bF[nb][1] = as_bf(*(const ushort8*)&smem[2+(BUF)][row*64 + (((4+g) ^ s7)*8)]);\
    }

  if (sel < 2){
    QKV_STAGE(0, 0);
    __syncthreads();
    #pragma unroll 1
    for (int it = 0; it < 16; ++it){
      const int cur = it & 1;
      if (it + 1 < 16) QKV_STAGE(cur^1, (it+1)*64);
      QKV_FRAGS(cur);
      #pragma unroll
      for (int mb = 0; mb < 4; mb++)
        #pragma unroll
        for (int nb = 0; nb < 4; nb++){
          acc[mb][nb] = MF(bF[nb][0], aF[mb][0], acc[mb][nb]);   // swapped: C^T
          acc[mb][nb] = MF(bF[nb][1], aF[mb][1], acc[mb][nb]);
        }
      __syncthreads();
    }
    unsigned short* dst0 = (sel == 0) ? qo : ko;
    const int nloc = (nbase & 1023) + wc*64;
    #pragma unroll
    for (int mb = 0; mb < 4; mb++){
      const int t = mbase + wr*64 + mb*16 + tl;
      const int b = t >> 11, tt = t & 2047;
      #pragma unroll
      for (int nb = 0; nb < 4; nb++){
        const int nw = nloc + nb*16 + g*4;
        const int h = nw >> 6, d0 = nw & 63;
        ushort4e pk;
        #pragma unroll
        for (int r = 0; r < 4; r++) pk[r] = f2b(acc[mb][nb][r]);
        *(ushort4e*)&dst0[(((size_t)(b*H_NUM + h))*T_SEQ + tt)*DHD + d0] = pk;
      }
    }
  } else {
    QKV_STAGE(0, 0);
    __syncthreads();
    #pragma unroll 1
    for (int it = 0; it < 16; ++it){
      const int cur = it & 1;
      if (it + 1 < 16) QKV_STAGE(cur^1, (it+1)*64);
      QKV_FRAGS(cur);
      #pragma unroll
      for (int mb = 0; mb < 4; mb++)
        #pragma unroll
        for (int nb = 0; nb < 4; nb++){
          acc[mb][nb] = MF(aF[mb][0], bF[nb][0], acc[mb][nb]);
          acc[mb][nb] = MF(aF[mb][1], bF[nb][1], acc[mb][nb]);
        }
      __syncthreads();
    }
    // V epilogue: transpose 128x128 tile through swizzled LDS, write sigma-permuted V^T.
    unsigned short* tr = &smem[0][0];      // 128*128 ushorts = 32 KB (aliases A bufs)
    #pragma unroll
    for (int mb = 0; mb < 4; mb++){
      #pragma unroll
      for (int nb = 0; nb < 4; nb++){
        const int n = wc*64 + nb*16 + tl;
        const int m0 = wr*64 + mb*16 + g*4;
        ushort4e pk;
        #pragma unroll
        for (int r = 0; r < 4; r++) pk[r] = f2b(acc[mb][nb][r]);
        *(ushort4e*)&tr[n*128 + (m0 ^ ((n & 15) << 3))] = pk;
      }
    }
    __syncthreads();
    const int hbase = (nbase - 2048) >> 6;
    const int b = mbase >> 11, tloc = mbase & 2047;
    const int n = tid >> 1, half = tid & 1;
    unsigned short* vdst = vtr + (((size_t)(b*H_NUM + hbase + (n >> 6)))*DHD + (n & 63))*T_SEQ
                           + tloc + half*64;
    const int nx = (n & 15) << 3;
    #pragma unroll
    for (int c8 = 0; c8 < 8; c8++){
      const int t0 = half*64 + (c8 >> 2)*32 + (c8 & 3)*4;
      ushort4e lo = *(const ushort4e*)&tr[n*128 + ((t0     ) ^ nx)];
      ushort4e hi = *(const ushort4e*)&tr[n*128 + ((t0 + 16) ^ nx)];
      ushort8 u;
      #pragma unroll
      for (int e = 0; e < 4; e++){ u[e] = lo[e]; u[4+e] = hi[e]; }
      *(ushort8*)&vdst[c8*8] = u;
    }
  }
#undef QKV_STAGE
#undef QKV_FRAGS
}

// ---------------- Flash attention (causal): 8 waves x 32 rows, one 256-row Q-tile/block ----------------
// grid 512 = 2 blocks/CU. Dispatch: k=id>>3 -> bh=8*(id&7)+(k&7), qsel=k>>3 pairs (q,q+4)
// -> qt = qsel<4 ? qsel : 11-qsel (co-resident pair sums 18 iters, shares bh).
// KVBLK=128; P in-register (sigma); V^T global sigma-permuted -> V frag = b128.
__global__ __launch_bounds__(512) void k_flash(const unsigned short* __restrict__ q,
                                               const unsigned short* __restrict__ k,
                                               const unsigned short* __restrict__ vtg,
                                               unsigned short* __restrict__ o){
  __shared__ __align__(16) unsigned short kbufs[2][128*64];   // [s][d]
  __shared__ __align__(16) unsigned short vbufs[2][64*128];   // [d][t-local]
  const int tid = threadIdx.x, lane = tid & 63, w = tid >> 6;
  const int g = lane >> 4, tl = lane & 15;
  const int id = blockIdx.x;
  const int kslot = id >> 3;
  const int bh = (id & 7)*8 + (kslot & 7);
  const int qsel = kslot >> 3;
  const int qt = (qsel < 4) ? qsel : (11 - qsel);
  const int b = bh >> 4, h = bh & 15;
  const unsigned short* qb = q   + (size_t)bh * T_SEQ * DHD;
  const unsigned short* kb = k   + (size_t)bh * T_SEQ * DHD;
  const unsigned short* vb = vtg + (size_t)bh * (size_t)DHD * T_SEQ;
  const int lrow = lane >> 3, lj = lane & 7;
  const int s7 = tl & 7;
  // V staging lane geometry
  const int vre = lane >> 4;            // row extra (0..3)
  const int vh  = (lane >> 3) & 1;      // col half
  const int vcc = lane & 7;             // chunk within half

  const int tbase = qt * 256;
  const int trow0 = tbase + w * 32;
  const int tmax = trow0 + 31;
  bf16x8 qF[2][2];
  #pragma unroll
  for (int tf = 0; tf < 2; tf++)
    #pragma unroll
    for (int ks = 0; ks < 2; ks++)
      qF[tf][ks] = as_bf(*(const ushort8*)&qb[(size_t)(trow0 + tf*16 + tl)*DHD + ks*32 + g*8]);
  f32x4 acc[2][4] = {};
  float mreg[2] = {-1e30f, -1e30f}, lreg[2] = {0.f, 0.f};
  const int nkt = 2*qt + 2;           // 128-wide kv tiles
  // prologue: stage tile 0 into buf 0
  #pragma unroll
  for (int i = 0; i < 2; i++){
    const int krow = i*64 + w*8 + lrow;
    const int kjj  = lj ^ (krow & 7);
    gload16(&kb[(size_t)krow*DHD + kjj*8], &kbufs[0][(i*64 + w*8)*64]);
    const int vrow = i*32 + w*4 + vre;
    const int vjj  = vcc ^ (vrow & 7);
    gload16(&vb[(size_t)vrow*T_SEQ + vh*64 + vjj*8], &vbufs[0][(i*32 + w*4)*128]);
  }
  __syncthreads();
  for (int kti = 0; kti < nkt; ++kti){
    const int cur = kti & 1;
    const int kbase = kti * 128;
    if (kti + 1 < nkt){
      const int kb2 = kbase + 128;
      #pragma unroll
      for (int i = 0; i < 2; i++){
        const int krow = i*64 + w*8 + lrow;
        const int kjj  = lj ^ (krow & 7);
        gload16(&kb[(size_t)(kb2+krow)*DHD + kjj*8], &kbufs[cur^1][(i*64 + w*8)*64]);
        const int vrow = i*32 + w*4 + vre;
        const int vjj  = vcc ^ (vrow & 7);
        gload16(&vb[(size_t)vrow*T_SEQ + kb2 + vh*64 + vjj*8], &vbufs[cur^1][(i*32 + w*4)*128]);
      }
    }
    if (kbase <= tmax){
      const unsigned short* kcur = kbufs[cur];
      const unsigned short* vcur = vbufs[cur];
      f32x4 st[2][8] = {};
      __builtin_amdgcn_s_setprio(1);
      #pragma unroll
      for (int sf = 0; sf < 8; sf++){
        const int row = sf*16 + tl;
        const int r7 = row & 7;
        bf16x8 kf0 = as_bf(*(const ushort8*)&kcur[row*64 + ((g     ^ r7)*8)]);
        bf16x8 kf1 = as_bf(*(const ushort8*)&kcur[row*64 + (((4+g) ^ r7)*8)]);
        #pragma unroll
        for (int tf = 0; tf < 2; tf++){
          st[tf][sf] = MF(kf0, qF[tf][0], st[tf][sf]);
          st[tf][sf] = MF(kf1, qF[tf][1], st[tf][sf]);
        }
      }
      __builtin_amdgcn_s_setprio(0);
      if (kbase + 127 > trow0){   // causal mask on near-diagonal tiles
        #pragma unroll
        for (int tf = 0; tf < 2; tf++){
          int tg = trow0 + tf*16 + tl;
          #pragma unroll
          for (int sf = 0; sf < 8; sf++)
            #pragma unroll
            for (int r = 0; r < 4; r++)
              if (kbase + sf*16 + g*4 + r > tg) st[tf][sf][r] = -1e30f;
        }
      }
      bf16x8 pa[2][4];
      #pragma unroll
      for (int tf = 0; tf < 2; tf++){
        float mloc = -1e30f;
        #pragma unroll
        for (int sf = 0; sf < 8; sf++)
          #pragma unroll
          for (int r = 0; r < 4; r++) mloc = fmaxf(mloc, st[tf][sf][r]);
        if (__any(mloc > mreg[tf] + 8.f)){   // lazy-max (T13)
          float mrow = fmaxf(mloc, __shfl_xor(mloc, 16));
          mrow = fmaxf(mrow, __shfl_xor(mrow, 32));
          float mnew = fmaxf(mreg[tf], mrow);
          float alpha = exp2fast(mreg[tf] - mnew);
          mreg[tf] = mnew;
          lreg[tf] *= alpha;
          #pragma unroll
          for (int df = 0; df < 4; df++)
            #pragma unroll
            for (int r = 0; r < 4; r++) acc[tf][df][r] *= alpha;
        }
        float sum = 0.f;
        #pragma unroll
        for (int q4 = 0; q4 < 4; q4++){
          ushort8 uu;
          #pragma unroll
          for (int r = 0; r < 4; r++){
            float p0 = exp2fast(st[tf][2*q4  ][r] - mreg[tf]);
            float p1 = exp2fast(st[tf][2*q4+1][r] - mreg[tf]);
            sum += p0 + p1;
            uu[r]   = f2b(p0);
            uu[4+r] = f2b(p1);
          }
          pa[tf][q4] = as_bf(uu);
        }
        lreg[tf] += sum;   // per-lane partial; reduced at epilogue
      }
      __builtin_amdgcn_s_setprio(1);
      #pragma unroll
      for (int df = 0; df < 4; df++){
        const int row = df*16 + tl;
        bf16x8 vfr[4];
        #pragma unroll
        for (int q4 = 0; q4 < 4; q4++)
          vfr[q4] = as_bf(*(const ushort8*)&vcur[row*128 + (q4 >> 1)*64 + (((4*(q4 & 1) + g) ^ s7)*8)]);
        #pragma unroll
        for (int tf = 0; tf < 2; tf++)
          #pragma unroll
          for (int q4 = 0; q4 < 4; q4++)
            acc[tf][df] = MF(vfr[q4], pa[tf][q4], acc[tf][df]);
      }
      __builtin_amdgcn_s_setprio(0);
    }
    __syncthreads();
  }
  #pragma unroll
  for (int tf = 0; tf < 2; tf++){
    float l = lreg[tf];
    l += __shfl_xor(l, 16);
    l += __shfl_xor(l, 32);
    float inv = 1.f / l;
    int tg = trow0 + tf*16 + tl;
    #pragma unroll
    for (int df = 0; df < 4; df++){
      ushort4e ov;
      #pragma unroll
      for (int r = 0; r < 4; r++) ov[r] = f2b(acc[tf][df][r] * inv);
      *(ushort4e*)&o[((size_t)(b*T_SEQ + tg))*C_DIM + h*DHD + df*16 + g*4] = ov;
    }
  }
}

// ---------------- GEMM: output projection + bias (1-barrier stage-ahead double-buffer) ----------------
__global__ __launch_bounds__(256) void k_gemm_proj(const unsigned short* __restrict__ ab,
                                                   const unsigned short* __restrict__ wot,
                                                   const float* __restrict__ bo,
                                                   float* __restrict__ out){
  __shared__ __align__(16) unsigned short smem[4][128*64];   // A:[0,1]  B:[2,3]  (64 KB)
  const int tid = threadIdx.x, lane = tid & 63, wid = tid >> 6;
  const int g = lane >> 4, tl = lane & 15;
  const int wr = wid >> 1, wc = wid & 1;
  const int id = blockIdx.x;
  const int swz = (id & 7)*64 + (id >> 3);
  const int mbase = (swz >> 3) * 128, nbase = (swz & 7) * 128;
  const int srow8 = lane >> 3, sj = lane & 7;
  f32x4 acc[4][4] = {};

#define PJ_STAGE(BUF, KK) do{                                                   \
    _Pragma("unroll")                                                           \
    for (int i2 = 0; i2 < 4; i2++){                                             \
      const int brow = (wid*4 + i2)*8;                                          \
      const int row  = brow + srow8;                                            \
      const int jj   = sj ^ (row & 7);                                          \
      gload16(&ab[(size_t)(mbase+row)*C_DIM + (KK) + jj*8],  &smem[BUF][brow*64]);   \
      gload16(&wot[(size_t)(nbase+row)*C_DIM + (KK) + jj*8], &smem[2+(BUF)][brow*64]);\
    }                                                                           \
  }while(0)

  PJ_STAGE(0, 0);
  __syncthreads();
  #pragma unroll 1
  for (int it = 0; it < 16; ++it){
    const int cur = it & 1;
    if (it + 1 < 16) PJ_STAGE(cur^1, (it+1)*64);
    bf16x8 aF[4][2], bF[4][2];
    #pragma unroll
    for (int mb = 0; mb < 4; mb++){
      const int row = wr*64 + mb*16 + tl; const int s7 = row & 7;
      aF[mb][0] = as_bf(*(const ushort8*)&smem[cur][row*64 + ((g     ^ s7)*8)]);
      aF[mb][1] = as_bf(*(const ushort8*)&smem[cur][row*64 + (((4+g) ^ s7)*8)]);
    }
    #pragma unroll
    for (int nb = 0; nb < 4; nb++){
      const int row = wc*64 + nb*16 + tl; const int s7 = row & 7;
      bF[nb][0] = as_bf(*(const ushort8*)&smem[2+cur][row*64 + ((g     ^ s7)*8)]);
      bF[nb][1] = as_bf(*(const ushort8*)&smem[2+cur][row*64 + (((4+g) ^ s7)*8)]);
    }
    #pragma unroll
    for (int mb = 0; mb < 4; mb++)
      #pragma unroll
      for (int nb = 0; nb < 4; nb++){
        acc[mb][nb] = MF(aF[mb][0], bF[nb][0], acc[mb][nb]);
        acc[mb][nb] = MF(aF[mb][1], bF[nb][1], acc[mb][nb]);
      }
    __syncthreads();
  }
#undef PJ_STAGE
  #pragma unroll
  for (int mb = 0; mb < 4; mb++){
    #pragma unroll
    for (int nb = 0; nb < 4; nb++){
      #pragma unroll
      for (int r = 0; r < 4; r++){
        int gr = mbase + wr*64 + mb*16 + g*4 + r;
        int gc = nbase + wc*64 + nb*16 + tl;
        out[(size_t)gr*C_DIM + gc] = acc[mb][nb][r] + bo[gc];
      }
    }
  }
}

extern "C" void kernel_launch(void* const* d_in, const int* in_sizes, int n_in,
                              void* d_out, int out_size, void* d_ws, size_t ws_size,
                              hipStream_t stream){
  const float* x  = (const float*)d_in[0];
  const float* Wq = (const float*)d_in[1];
  const float* Wk = (const float*)d_in[2];
  const float* Wv = (const float*)d_in[3];
  const float* Wo = (const float*)d_in[4];
  const float* bo = (const float*)d_in[5];
  float* out = (float*)d_out;

  char* p = (char*)d_ws;
  unsigned short* xb  = (unsigned short*)p; p += (size_t)M_ROWS*C_DIM*2;   // 16MB
  unsigned short* wt  = (unsigned short*)p; p += (size_t)3*C_DIM*C_DIM*2;  // 6MB
  unsigned short* wot = (unsigned short*)p; p += (size_t)C_DIM*C_DIM*2;    // 2MB
  unsigned short* Qb  = (unsigned short*)p; p += (size_t)M_ROWS*C_DIM*2;   // 16MB
  unsigned short* Kb  = (unsigned short*)p; p += (size_t)M_ROWS*C_DIM*2;   // 16MB
  unsigned short* Vtr = (unsigned short*)p; p += (size_t)M_ROWS*C_DIM*2;   // 16MB (sigma-permuted V^T)
  unsigned short* attn = xb;   // reuse: xb dead after k_gemm_qkv

  hipLaunchKernelGGL(k_prep, dim3(8192 + 1024), dim3(256), 0, stream,
                     x, Wq, Wk, Wv, Wo, xb, wt, wot);
  hipLaunchKernelGGL(k_gemm_qkv, dim3(1536), dim3(256), 0, stream,
                     xb, wt, Qb, Kb, Vtr);
  hipLaunchKernelGGL(k_flash, dim3(512), dim3(512), 0, stream,
                     Qb, Kb, Vtr, attn);
  hipLaunchKernelGGL(k_gemm_proj, dim3(512), dim3(256), 0, stream,
                     attn, wot, bo, out);
}

// Round 25
// 156.612 us; speedup vs baseline: 1.0452x; 1.0019x over previous
//
#include <hip/hip_runtime.h>

// MHA fused forward: B=4, T=2048, C=1024, H=16, DH=64
#define T_SEQ 2048
#define C_DIM 1024
#define H_NUM 16
#define DHD   64
#define B_NUM 4
#define M_ROWS (B_NUM*T_SEQ)   // 8192

typedef __bf16 bf16x8 __attribute__((ext_vector_type(8)));
typedef float  f32x4  __attribute__((ext_vector_type(4)));
typedef unsigned short ushort8 __attribute__((ext_vector_type(8)));
typedef unsigned short ushort4e __attribute__((ext_vector_type(4)));

__device__ __forceinline__ unsigned short f2b(float f){
  return __builtin_bit_cast(unsigned short, (__bf16)f);
}
__device__ __forceinline__ bf16x8 as_bf(ushort8 u){ return __builtin_bit_cast(bf16x8, u); }
__device__ __forceinline__ float exp2fast(float x){ return __builtin_amdgcn_exp2f(x); }

__device__ __forceinline__ void gload16(const void* g, void* l){
  __builtin_amdgcn_global_load_lds(
      (const __attribute__((address_space(1))) void*)g,
      (__attribute__((address_space(3))) void*)l, 16, 0, 0);
}

#define MF(a,b,c) __builtin_amdgcn_mfma_f32_16x16x32_bf16(a,b,c,0,0,0)

// ---------------- prep: x f32->bf16 (8/thread) + coalesced weight pack (LDS transpose) ----------------
__global__ __launch_bounds__(256) void k_prep(const float* __restrict__ x,
                                              const float* __restrict__ wq,
                                              const float* __restrict__ wk,
                                              const float* __restrict__ wv,
                                              const float* __restrict__ wo,
                                              unsigned short* __restrict__ xb,
                                              unsigned short* __restrict__ wt,
                                              unsigned short* __restrict__ wot){
  const int bid = blockIdx.x;
  const int tid = threadIdx.x;
  if (bid < 4096){
    int i = bid*256 + tid;
    float4 f0 = ((const float4*)x)[2*i];
    float4 f1 = ((const float4*)x)[2*i + 1];
    ushort8 o;
    o[0]=f2b(f0.x); o[1]=f2b(f0.y); o[2]=f2b(f0.z); o[3]=f2b(f0.w);
    o[4]=f2b(f1.x); o[5]=f2b(f1.y); o[6]=f2b(f1.z); o[7]=f2b(f1.w);
    ((ushort8*)xb)[i] = o;
    return;
  }
  __shared__ __align__(16) unsigned short vr[64][72];
  const int tb = bid - 4096;
  const float* S; int LS; unsigned short* D; int R0, C0; float scale = 1.f;
  if (tb < 768){
    int m = tb >> 8, rem = tb & 255;
    int h = rem >> 4, c0 = rem & 15;
    S = ((m==0)?wq:(m==1)?wk:wv) + (size_t)(h*16 + c0)*64*64;
    LS = 64;
    D = wt; R0 = m*1024 + h*64; C0 = c0*64;
    if (m == 0) scale = 0.125f * 1.4426950408889634f;  // DH^-0.5 * log2(e)
  } else {
    int tb2 = tb - 768;
    int nb = tb2 >> 4, cb = tb2 & 15;
    S = wo + (size_t)(cb*64)*1024 + nb*64;
    LS = 1024;
    D = wot; R0 = nb*64; C0 = cb*64;
  }
  #pragma unroll
  for (int i = 0; i < 2; i++){
    int id2 = tid + i*256;
    int r = id2 >> 3, e8 = (id2 & 7)*8;
    float4 a = *(const float4*)&S[(size_t)r*LS + e8];
    float4 b2 = *(const float4*)&S[(size_t)r*LS + e8 + 4];
    ushort8 u;
    u[0]=f2b(a.x*scale); u[1]=f2b(a.y*scale); u[2]=f2b(a.z*scale); u[3]=f2b(a.w*scale);
    u[4]=f2b(b2.x*scale); u[5]=f2b(b2.y*scale); u[6]=f2b(b2.z*scale); u[7]=f2b(b2.w*scale);
    *(ushort8*)&vr[r][e8 ^ ((r >> 3) << 3)] = u;
  }
  __syncthreads();
  #pragma unroll
  for (int i = 0; i < 2; i++){
    int id2 = tid + i*256;
    int d = id2 >> 3, oc = id2 & 7;
    ushort8 u;
    #pragma unroll
    for (int j = 0; j < 8; j++)
      u[j] = vr[oc*8 + j][d ^ (oc << 3)];
    *(ushort8*)&D[(size_t)(R0 + d)*1024 + C0 + oc*8] = u;
  }
}

// ---------------- GEMM: QKV projection (1-barrier stage-ahead double-buffer) ----------------
// Per K-step: stage(next tile -> buf^1) issued FIRST, then frag-reads+MFMA on buf, then
// ONE __syncthreads() (its vmcnt drain overlaps the compute). Q/K blocks compute C^T
// (swapped MFMA) -> ushort4 stores; V blocks keep orientation + sigma-permuted V^T epilogue.
__global__ __launch_bounds__(256) void k_gemm_qkv(const unsigned short* __restrict__ xb,
                                                  const unsigned short* __restrict__ wt,
                                                  unsigned short* __restrict__ qo,
                                                  unsigned short* __restrict__ ko,
                                                  unsigned short* __restrict__ vtr){
  __shared__ __align__(16) unsigned short smem[4][128*64];   // A:[0,1]  B:[2,3]  (64 KB)
  const int tid = threadIdx.x, lane = tid & 63, wid = tid >> 6;
  const int g = lane >> 4, tl = lane & 15;
  const int wr = wid >> 1, wc = wid & 1;
  const int id = blockIdx.x;
  const int xcd = id & 7, i = id >> 3;        // 192 blocks per XCD
  const int xm = xcd >> 1, xn = xcd & 1;
  const int mbase = (xm*16 + i/12) * 128, nbase = (xn*12 + i%12) * 128;
  const int sel = nbase >> 10;   // block-uniform
  const int srow8 = lane >> 3, sj = lane & 7;
  f32x4 acc[4][4] = {};

#define QKV_STAGE(BUF, KK) do{                                                  \
    _Pragma("unroll")                                                           \
    for (int i2 = 0; i2 < 4; i2++){                                             \
      const int brow = (wid*4 + i2)*8;                                          \
      const int row  = brow + srow8;                                            \
      const int jj   = sj ^ (row & 7);                                          \
      gload16(&xb[(size_t)(mbase+row)*C_DIM + (KK) + jj*8], &smem[BUF][brow*64]);   \
      gload16(&wt[(size_t)(nbase+row)*C_DIM + (KK) + jj*8], &smem[2+(BUF)][brow*64]);\
    }                                                                           \
  }while(0)

#define QKV_FRAGS(BUF)                                                          \
    bf16x8 aF[4][2], bF[4][2];                                                  \
    _Pragma("unroll")                                                           \
    for (int mb = 0; mb < 4; mb++){                                             \
      const int row = wr*64 + mb*16 + tl; const int s7 = row & 7;               \
      aF[mb][0] = as_bf(*(const ushort8*)&smem[BUF][row*64 + ((g     ^ s7)*8)]);\
      aF[mb][1] = as_bf(*(const ushort8*)&smem[BUF][row*64 + (((4+g) ^ s7)*8)]);\
    }                                                                           \
    _Pragma("unroll")                                                           \
    for (int nb = 0; nb < 4; nb++){                                             \
      const int row = wc*64 + nb*16 + tl; const int s7 = row & 7;               \
      bF[nb][0] = as_bf(*(const ushort8*)&smem[2+(BUF)][row*64 + ((g     ^ s7)*8)]);\
      bF[nb][1] = as_bf(*(const ushort8*)&smem[2+(BUF)][row*64 + (((4+g) ^ s7)*8)]);\
    }

  if (sel < 2){
    QKV_STAGE(0, 0);
    __syncthreads();
    #pragma unroll 1
    for (int it = 0; it < 16; ++it){
      const int cur = it & 1;
      if (it + 1 < 16) QKV_STAGE(cur^1, (it+1)*64);
      QKV_FRAGS(cur);
      #pragma unroll
      for (int mb = 0; mb < 4; mb++)
        #pragma unroll
        for (int nb = 0; nb < 4; nb++){
          acc[mb][nb] = MF(bF[nb][0], aF[mb][0], acc[mb][nb]);   // swapped: C^T
          acc[mb][nb] = MF(bF[nb][1], aF[mb][1], acc[mb][nb]);
        }
      __syncthreads();
    }
    unsigned short* dst0 = (sel == 0) ? qo : ko;
    const int nloc = (nbase & 1023) + wc*64;
    #pragma unroll
    for (int mb = 0; mb < 4; mb++){
      const int t = mbase + wr*64 + mb*16 + tl;
      const int b = t >> 11, tt = t & 2047;
      #pragma unroll
      for (int nb = 0; nb < 4; nb++){
        const int nw = nloc + nb*16 + g*4;
        const int h = nw >> 6, d0 = nw & 63;
        ushort4e pk;
        #pragma unroll
        for (int r = 0; r < 4; r++) pk[r] = f2b(acc[mb][nb][r]);
        *(ushort4e*)&dst0[(((size_t)(b*H_NUM + h))*T_SEQ + tt)*DHD + d0] = pk;
      }
    }
  } else {
    QKV_STAGE(0, 0);
    __syncthreads();
    #pragma unroll 1
    for (int it = 0; it < 16; ++it){
      const int cur = it & 1;
      if (it + 1 < 16) QKV_STAGE(cur^1, (it+1)*64);
      QKV_FRAGS(cur);
      #pragma unroll
      for (int mb = 0; mb < 4; mb++)
        #pragma unroll
        for (int nb = 0; nb < 4; nb++){
          acc[mb][nb] = MF(aF[mb][0], bF[nb][0], acc[mb][nb]);
          acc[mb][nb] = MF(aF[mb][1], bF[nb][1], acc[mb][nb]);
        }
      __syncthreads();
    }
    // V epilogue: transpose 128x128 tile through swizzled LDS, write sigma-permuted V^T.
    unsigned short* tr = &smem[0][0];      // 128*128 ushorts = 32 KB (aliases A bufs)
    #pragma unroll
    for (int mb = 0; mb < 4; mb++){
      #pragma unroll
      for (int nb = 0; nb < 4; nb++){
        const int n = wc*64 + nb*16 + tl;
        const int m0 = wr*64 + mb*16 + g*4;
        ushort4e pk;
        #pragma unroll
        for (int r = 0; r < 4; r++) pk[r] = f2b(acc[mb][nb][r]);
        *(ushort4e*)&tr[n*128 + (m0 ^ ((n & 15) << 3))] = pk;
      }
    }
    __syncthreads();
    const int hbase = (nbase - 2048) >> 6;
    const int b = mbase >> 11, tloc = mbase & 2047;
    const int n = tid >> 1, half = tid & 1;
    unsigned short* vdst = vtr + (((size_t)(b*H_NUM + hbase + (n >> 6)))*DHD + (n & 63))*T_SEQ
                           + tloc + half*64;
    const int nx = (n & 15) << 3;
    #pragma unroll
    for (int c8 = 0; c8 < 8; c8++){
      const int t0 = half*64 + (c8 >> 2)*32 + (c8 & 3)*4;
      ushort4e lo = *(const ushort4e*)&tr[n*128 + ((t0     ) ^ nx)];
      ushort4e hi = *(const ushort4e*)&tr[n*128 + ((t0 + 16) ^ nx)];
      ushort8 u;
      #pragma unroll
      for (int e = 0; e < 4; e++){ u[e] = lo[e]; u[4+e] = hi[e]; }
      *(ushort8*)&vdst[c8*8] = u;
    }
  }
#undef QKV_STAGE
#undef QKV_FRAGS
}

// ---------------- Flash attention (causal): 8 waves x 32 rows, one 256-row Q-tile/block ----------------
// grid 512 = 2 blocks/CU. Dispatch: k=id>>3 -> bh=8*(id&7)+(k&7), qsel=k>>3 pairs (q,q+4)
// -> qt = qsel<4 ? qsel : 11-qsel (co-resident pair sums 18 iters, shares bh).
// KVBLK=128; P in-register (sigma); V^T global sigma-permuted -> V frag = b128.
__global__ __launch_bounds__(512) void k_flash(const unsigned short* __restrict__ q,
                                               const unsigned short* __restrict__ k,
                                               const unsigned short* __restrict__ vtg,
                                               unsigned short* __restrict__ o){
  __shared__ __align__(16) unsigned short kbufs[2][128*64];   // [s][d]
  __shared__ __align__(16) unsigned short vbufs[2][64*128];   // [d][t-local]
  const int tid = threadIdx.x, lane = tid & 63, w = tid >> 6;
  const int g = lane >> 4, tl = lane & 15;
  const int id = blockIdx.x;
  const int kslot = id >> 3;
  const int bh = (id & 7)*8 + (kslot & 7);
  const int qsel = kslot >> 3;
  const int qt = (qsel < 4) ? qsel : (11 - qsel);
  const int b = bh >> 4, h = bh & 15;
  const unsigned short* qb = q   + (size_t)bh * T_SEQ * DHD;
  const unsigned short* kb = k   + (size_t)bh * T_SEQ * DHD;
  const unsigned short* vb = vtg + (size_t)bh * (size_t)DHD * T_SEQ;
  const int lrow = lane >> 3, lj = lane & 7;
  const int s7 = tl & 7;
  // V staging lane geometry
  const int vre = lane >> 4;            // row extra (0..3)
  const int vh  = (lane >> 3) & 1;      // col half
  const int vcc = lane & 7;             // chunk within half

  const int tbase = qt * 256;
  const int trow0 = tbase + w * 32;
  const int tmax = trow0 + 31;
  bf16x8 qF[2][2];
  #pragma unroll
  for (int tf = 0; tf < 2; tf++)
    #pragma unroll
    for (int ks = 0; ks < 2; ks++)
      qF[tf][ks] = as_bf(*(const ushort8*)&qb[(size_t)(trow0 + tf*16 + tl)*DHD + ks*32 + g*8]);
  f32x4 acc[2][4] = {};
  float mreg[2] = {-1e30f, -1e30f}, lreg[2] = {0.f, 0.f};
  const int nkt = 2*qt + 2;           // 128-wide kv tiles
  // prologue: stage tile 0 into buf 0
  #pragma unroll
  for (int i = 0; i < 2; i++){
    const int krow = i*64 + w*8 + lrow;
    const int kjj  = lj ^ (krow & 7);
    gload16(&kb[(size_t)krow*DHD + kjj*8], &kbufs[0][(i*64 + w*8)*64]);
    const int vrow = i*32 + w*4 + vre;
    const int vjj  = vcc ^ (vrow & 7);
    gload16(&vb[(size_t)vrow*T_SEQ + vh*64 + vjj*8], &vbufs[0][(i*32 + w*4)*128]);
  }
  __syncthreads();
  for (int kti = 0; kti < nkt; ++kti){
    const int cur = kti & 1;
    const int kbase = kti * 128;
    if (kti + 1 < nkt){
      const int kb2 = kbase + 128;
      #pragma unroll
      for (int i = 0; i < 2; i++){
        const int krow = i*64 + w*8 + lrow;
        const int kjj  = lj ^ (krow & 7);
        gload16(&kb[(size_t)(kb2+krow)*DHD + kjj*8], &kbufs[cur^1][(i*64 + w*8)*64]);
        const int vrow = i*32 + w*4 + vre;
        const int vjj  = vcc ^ (vrow & 7);
        gload16(&vb[(size_t)vrow*T_SEQ + kb2 + vh*64 + vjj*8], &vbufs[cur^1][(i*32 + w*4)*128]);
      }
    }
    if (kbase <= tmax){
      const unsigned short* kcur = kbufs[cur];
      const unsigned short* vcur = vbufs[cur];
      f32x4 st[2][8] = {};
      __builtin_amdgcn_s_setprio(1);
      #pragma unroll
      for (int sf = 0; sf < 8; sf++){
        const int row = sf*16 + tl;
        const int r7 = row & 7;
        bf16x8 kf0 = as_bf(*(const ushort8*)&kcur[row*64 + ((g     ^ r7)*8)]);
        bf16x8 kf1 = as_bf(*(const ushort8*)&kcur[row*64 + (((4+g) ^ r7)*8)]);
        #pragma unroll
        for (int tf = 0; tf < 2; tf++){
          st[tf][sf] = MF(kf0, qF[tf][0], st[tf][sf]);
          st[tf][sf] = MF(kf1, qF[tf][1], st[tf][sf]);
        }
      }
      __builtin_amdgcn_s_setprio(0);
      if (kbase + 127 > trow0){   // causal mask on near-diagonal tiles
        #pragma unroll
        for (int tf = 0; tf < 2; tf++){
          int tg = trow0 + tf*16 + tl;
          #pragma unroll
          for (int sf = 0; sf < 8; sf++)
            #pragma unroll
            for (int r = 0; r < 4; r++)
              if (kbase + sf*16 + g*4 + r > tg) st[tf][sf][r] = -1e30f;
        }
      }
      bf16x8 pa[2][4];
      #pragma unroll
      for (int tf = 0; tf < 2; tf++){
        float mloc = -1e30f;
        #pragma unroll
        for (int sf = 0; sf < 8; sf++)
          #pragma unroll
          for (int r = 0; r < 4; r++) mloc = fmaxf(mloc, st[tf][sf][r]);
        if (__any(mloc > mreg[tf] + 8.f)){   // lazy-max (T13)
          float mrow = fmaxf(mloc, __shfl_xor(mloc, 16));
          mrow = fmaxf(mrow, __shfl_xor(mrow, 32));
          float mnew = fmaxf(mreg[tf], mrow);
          float alpha = exp2fast(mreg[tf] - mnew);
          mreg[tf] = mnew;
          lreg[tf] *= alpha;
          #pragma unroll
          for (int df = 0; df < 4; df++)
            #pragma unroll
            for (int r = 0; r < 4; r++) acc[tf][df][r] *= alpha;
        }
        float sum = 0.f;
        #pragma unroll
        for (int q4 = 0; q4 < 4; q4++){
          ushort8 uu;
          #pragma unroll
          for (int r = 0; r < 4; r++){
            float p0 = exp2fast(st[tf][2*q4  ][r] - mreg[tf]);
            float p1 = exp2fast(st[tf][2*q4+1][r] - mreg[tf]);
            sum += p0 + p1;
            uu[r]   = f2b(p0);
            uu[4+r] = f2b(p1);
          }
          pa[tf][q4] = as_bf(uu);
        }
        lreg[tf] += sum;   // per-lane partial; reduced at epilogue
      }
      __builtin_amdgcn_s_setprio(1);
      #pragma unroll
      for (int df = 0; df < 4; df++){
        const int row = df*16 + tl;
        bf16x8 vfr[4];
        #pragma unroll
        for (int q4 = 0; q4 < 4; q4++)
          vfr[q4] = as_bf(*(const ushort8*)&vcur[row*128 + (q4 >> 1)*64 + (((4*(q4 & 1) + g) ^ s7)*8)]);
        #pragma unroll
        for (int tf = 0; tf < 2; tf++)
          #pragma unroll
          for (int q4 = 0; q4 < 4; q4++)
            acc[tf][df] = MF(vfr[q4], pa[tf][q4], acc[tf][df]);
      }
      __builtin_amdgcn_s_setprio(0);
    }
    __syncthreads();
  }
  #pragma unroll
  for (int tf = 0; tf < 2; tf++){
    float l = lreg[tf];
    l += __shfl_xor(l, 16);
    l += __shfl_xor(l, 32);
    float inv = 1.f / l;
    int tg = trow0 + tf*16 + tl;
    #pragma unroll
    for (int df = 0; df < 4; df++){
      ushort4e ov;
      #pragma unroll
      for (int r = 0; r < 4; r++) ov[r] = f2b(acc[tf][df][r] * inv);
      *(ushort4e*)&o[((size_t)(b*T_SEQ + tg))*C_DIM + h*DHD + df*16 + g*4] = ov;
    }
  }
}

// ---------------- GEMM: output projection + bias (1-barrier stage-ahead double-buffer) ----------------
__global__ __launch_bounds__(256) void k_gemm_proj(const unsigned short* __restrict__ ab,
                                                   const unsigned short* __restrict__ wot,
                                                   const float* __restrict__ bo,
                                                   float* __restrict__ out){
  __shared__ __align__(16) unsigned short smem[4][128*64];   // A:[0,1]  B:[2,3]  (64 KB)
  const int tid = threadIdx.x, lane = tid & 63, wid = tid >> 6;
  const int g = lane >> 4, tl = lane & 15;
  const int wr = wid >> 1, wc = wid & 1;
  const int id = blockIdx.x;
  const int swz = (id & 7)*64 + (id >> 3);
  const int mbase = (swz >> 3) * 128, nbase = (swz & 7) * 128;
  const int srow8 = lane >> 3, sj = lane & 7;
  f32x4 acc[4][4] = {};

#define PJ_STAGE(BUF, KK) do{                                                   \
    _Pragma("unroll")                                                           \
    for (int i2 = 0; i2 < 4; i2++){                                             \
      const int brow = (wid*4 + i2)*8;                                          \
      const int row  = brow + srow8;                                            \
      const int jj   = sj ^ (row & 7);                                          \
      gload16(&ab[(size_t)(mbase+row)*C_DIM + (KK) + jj*8],  &smem[BUF][brow*64]);   \
      gload16(&wot[(size_t)(nbase+row)*C_DIM + (KK) + jj*8], &smem[2+(BUF)][brow*64]);\
    }                                                                           \
  }while(0)

  PJ_STAGE(0, 0);
  __syncthreads();
  #pragma unroll 1
  for (int it = 0; it < 16; ++it){
    const int cur = it & 1;
    if (it + 1 < 16) PJ_STAGE(cur^1, (it+1)*64);
    bf16x8 aF[4][2], bF[4][2];
    #pragma unroll
    for (int mb = 0; mb < 4; mb++){
      const int row = wr*64 + mb*16 + tl; const int s7 = row & 7;
      aF[mb][0] = as_bf(*(const ushort8*)&smem[cur][row*64 + ((g     ^ s7)*8)]);
      aF[mb][1] = as_bf(*(const ushort8*)&smem[cur][row*64 + (((4+g) ^ s7)*8)]);
    }
    #pragma unroll
    for (int nb = 0; nb < 4; nb++){
      const int row = wc*64 + nb*16 + tl; const int s7 = row & 7;
      bF[nb][0] = as_bf(*(const ushort8*)&smem[2+cur][row*64 + ((g     ^ s7)*8)]);
      bF[nb][1] = as_bf(*(const ushort8*)&smem[2+cur][row*64 + (((4+g) ^ s7)*8)]);
    }
    #pragma unroll
    for (int mb = 0; mb < 4; mb++)
      #pragma unroll
      for (int nb = 0; nb < 4; nb++){
        acc[mb][nb] = MF(aF[mb][0], bF[nb][0], acc[mb][nb]);
        acc[mb][nb] = MF(aF[mb][1], bF[nb][1], acc[mb][nb]);
      }
    __syncthreads();
  }
#undef PJ_STAGE
  #pragma unroll
  for (int mb = 0; mb < 4; mb++){
    #pragma unroll
    for (int nb = 0; nb < 4; nb++){
      #pragma unroll
      for (int r = 0; r < 4; r++){
        int gr = mbase + wr*64 + mb*16 + g*4 + r;
        int gc = nbase + wc*64 + nb*16 + tl;
        out[(size_t)gr*C_DIM + gc] = acc[mb][nb][r] + bo[gc];
      }
    }
  }
}

extern "C" void kernel_launch(void* const* d_in, const int* in_sizes, int n_in,
                              void* d_out, int out_size, void* d_ws, size_t ws_size,
                              hipStream_t stream){
  const float* x  = (const float*)d_in[0];
  const float* Wq = (const float*)d_in[1];
  const float* Wk = (const float*)d_in[2];
  const float* Wv = (const float*)d_in[3];
  const float* Wo = (const float*)d_in[4];
  const float* bo = (const float*)d_in[5];
  float* out = (float*)d_out;

  char* p = (char*)d_ws;
  unsigned short* xb  = (unsigned short*)p; p += (size_t)M_ROWS*C_DIM*2;   // 16MB
  unsigned short* wt  = (unsigned short*)p; p += (size_t)3*C_DIM*C_DIM*2;  // 6MB
  unsigned short* wot = (unsigned short*)p; p += (size_t)C_DIM*C_DIM*2;    // 2MB
  unsigned short* Qb  = (unsigned short*)p; p += (size_t)M_ROWS*C_DIM*2;   // 16MB
  unsigned short* Kb  = (unsigned short*)p; p += (size_t)M_ROWS*C_DIM*2;   // 16MB
  unsigned short* Vtr = (unsigned short*)p; p += (size_t)M_ROWS*C_DIM*2;   // 16MB (sigma-permuted V^T)
  unsigned short* attn = xb;   // reuse: xb dead after k_gemm_qkv

  hipLaunchKernelGGL(k_prep, dim3(4096 + 1024), dim3(256), 0, stream,
                     x, Wq, Wk, Wv, Wo, xb, wt, wot);
  hipLaunchKernelGGL(k_gemm_qkv, dim3(1536), dim3(256), 0, stream,
                     xb, wt, Qb, Kb, Vtr);
  hipLaunchKernelGGL(k_flash, dim3(512), dim3(512), 0, stream,
                     Qb, Kb, Vtr, attn);
  hipLaunchKernelGGL(k_gemm_proj, dim3(512), dim3(256), 0, stream,
                     attn, wot, bo, out);
}